// Round 1
// baseline (525.896 us; speedup 1.0000x reference)
//
#include <hip/hip_runtime.h>

#define NB     8
#define TNEW   1024
#define TCACHE 3072
#define TTOT   4096
#define EMB    512
#define HD     64

// ---------------- kernel 1: copy caches into k/v output sections ----------------
__global__ __launch_bounds__(256) void copy_cache(const float* __restrict__ ck,
                                                  const float* __restrict__ cv,
                                                  float* __restrict__ kout,
                                                  float* __restrict__ vout) {
    const int i = blockIdx.x * 256 + threadIdx.x;   // float4 index; total = 8*3072*64/4 = 393216
    const int per_b = TCACHE * HD / 4;              // 49152
    const int b = i / per_b;
    const int r = i - b * per_b;
    const float4* ck4 = (const float4*)ck;
    const float4* cv4 = (const float4*)cv;
    float4* k4 = (float4*)(kout + (size_t)b * TTOT * HD);
    float4* v4 = (float4*)(vout + (size_t)b * TTOT * HD);
    k4[r] = ck4[i];
    v4[r] = cv4[i];
}

// ---------------- kernel 2: QKV projections ----------------
// q -> qbuf (aliased with `out` section; overwritten later by attn)
// k_new/v_new -> k/v sections at time offset TCACHE
#define PR_ROWS 32
__global__ __launch_bounds__(256) void proj(const float* __restrict__ x,
                                            const float* __restrict__ Wq,
                                            const float* __restrict__ Wk,
                                            const float* __restrict__ Wv,
                                            float* __restrict__ qout,
                                            float* __restrict__ kout,
                                            float* __restrict__ vout) {
    __shared__ float xs[PR_ROWS][EMB];   // 64 KB
    const int tid = threadIdx.x;
    const size_t base = (size_t)blockIdx.x * PR_ROWS * EMB;
    const float4* xg = (const float4*)(x + base);
    float4* xs4 = (float4*)&xs[0][0];
#pragma unroll
    for (int i = 0; i < 16; ++i)          // 32*512/4 = 4096 float4 / 256 thr = 16 each
        xs4[tid + 256 * i] = xg[tid + 256 * i];
    __syncthreads();

    const int w = tid >> 6, lane = tid & 63;
    for (int r8 = 0; r8 < 8; ++r8) {
        const int r = w * 8 + r8;
        float aq = 0.f, ak = 0.f, av = 0.f;
#pragma unroll 4
        for (int c = 0; c < EMB; ++c) {
            const float xv = xs[r][c];
            aq = fmaf(xv, Wq[c * HD + lane], aq);
            ak = fmaf(xv, Wk[c * HD + lane], ak);
            av = fmaf(xv, Wv[c * HD + lane], av);
        }
        const int row = blockIdx.x * PR_ROWS + r;   // 0..8191
        const int b = row >> 10;
        const int t = row & (TNEW - 1);
        qout[(size_t)row * HD + lane] = aq;
        const size_t kv = ((size_t)b * TTOT + TCACHE + t) * HD + lane;
        kout[kv] = ak;
        vout[kv] = av;
    }
}

// ---------------- kernel 3: flash attention (f32) ----------------
#define AW   4      // waves per block
#define RPW  8      // query rows per wave
#define BROWS (AW * RPW)   // 32 rows per block
#define KT   64     // key tile

__global__ __launch_bounds__(256) void attn(const float* __restrict__ q,
                                            const float* __restrict__ kk,
                                            const float* __restrict__ vv,
                                            float* __restrict__ out) {
    __shared__ float Ks[KT * HD];          // 16 KB, 16B-slot XOR-swizzled rows
    __shared__ float Vs[KT * HD];          // 16 KB, linear
    __shared__ float qs[BROWS * HD];       // 8 KB
    __shared__ float ps[AW][KT][RPW];      // 8 KB

    const int tid = threadIdx.x;
    const int w = tid >> 6, lane = tid & 63;
    const int row0 = blockIdx.x * BROWS;
    const int b = row0 >> 10;
    const int t0 = row0 & (TNEW - 1);

    {   // stage q tile: 32*64 = 2048 floats = 512 float4
        const float4* qg = (const float4*)(q + (size_t)row0 * HD);
        float4* qs4 = (float4*)qs;
        qs4[tid] = qg[tid];
        qs4[tid + 256] = qg[tid + 256];
    }

    const float* kb = kk + (size_t)b * TTOT * HD;
    const float* vb = vv + (size_t)b * TTOT * HD;

    float m[RPW], l[RPW], acc[RPW];
#pragma unroll
    for (int i = 0; i < RPW; ++i) { m[i] = -1e30f; l[i] = 0.f; acc[i] = 0.f; }

    const int ntiles = (TCACHE + t0 + BROWS + KT - 1) >> 6;   // covers s <= 3072 + t0 + 31

    for (int tile = 0; tile < ntiles; ++tile) {
        const int s0 = tile << 6;
        __syncthreads();   // protect prev iteration's readers before overwrite
        {   // stage K (swizzled) and V (linear): 1024 float4 each, 4 per thread
            const float4* kg = (const float4*)(kb + (size_t)s0 * HD);
            const float4* vg = (const float4*)(vb + (size_t)s0 * HD);
            float4* Vs4 = (float4*)Vs;
#pragma unroll
            for (int i = 0; i < 4; ++i) {
                const int f = tid + 256 * i;      // 0..1023
                const int s = f >> 4, g = f & 15;
                const float4 kd = kg[f];
                const float4 vd = vg[f];
                const int gs = (g & 8) | ((g & 7) ^ (s & 7));
                *(float4*)&Ks[s * HD + gs * 4] = kd;
                Vs4[f] = vd;
            }
        }
        __syncthreads();

        // ---- scores: lane owns key s' = lane ----
        float sc[RPW];
#pragma unroll
        for (int i = 0; i < RPW; ++i) sc[i] = 0.f;
#pragma unroll
        for (int g = 0; g < 16; ++g) {
            const int gs = (g & 8) | ((g & 7) ^ (lane & 7));
            const float4 k4 = *(const float4*)&Ks[lane * HD + gs * 4];
#pragma unroll
            for (int rr = 0; rr < RPW; ++rr) {
                const float4 q4 = *(const float4*)&qs[(w * RPW + rr) * HD + g * 4];
                sc[rr] = fmaf(q4.x, k4.x, sc[rr]);
                sc[rr] = fmaf(q4.y, k4.y, sc[rr]);
                sc[rr] = fmaf(q4.z, k4.z, sc[rr]);
                sc[rr] = fmaf(q4.w, k4.w, sc[rr]);
            }
        }

        // ---- online softmax per row ----
        float pfrag[RPW];
#pragma unroll
        for (int rr = 0; rr < RPW; ++rr) {
            const int t = t0 + w * RPW + rr;
            const bool valid = (s0 + lane) <= (TCACHE + t);
            const float s = valid ? sc[rr] * 0.125f : -1e30f;
            float mt = s;
#pragma unroll
            for (int off = 32; off > 0; off >>= 1)
                mt = fmaxf(mt, __shfl_xor(mt, off));
            const float mn = fmaxf(m[rr], mt);
            const float p = valid ? __expf(s - mn) : 0.f;
            float psum = p;
#pragma unroll
            for (int off = 32; off > 0; off >>= 1)
                psum += __shfl_xor(psum, off);
            const float corr = __expf(m[rr] - mn);
            l[rr] = l[rr] * corr + psum;
            acc[rr] *= corr;
            m[rr] = mn;
            pfrag[rr] = p;
        }
        *(float4*)&ps[w][lane][0] = make_float4(pfrag[0], pfrag[1], pfrag[2], pfrag[3]);
        *(float4*)&ps[w][lane][4] = make_float4(pfrag[4], pfrag[5], pfrag[6], pfrag[7]);

        // ---- PV: lane owns dim d = lane ----
#pragma unroll 8
        for (int s = 0; s < KT; ++s) {
            const float vval = Vs[s * HD + lane];
            const float4 p40 = *(const float4*)&ps[w][s][0];
            const float4 p41 = *(const float4*)&ps[w][s][4];
            acc[0] = fmaf(p40.x, vval, acc[0]);
            acc[1] = fmaf(p40.y, vval, acc[1]);
            acc[2] = fmaf(p40.z, vval, acc[2]);
            acc[3] = fmaf(p40.w, vval, acc[3]);
            acc[4] = fmaf(p41.x, vval, acc[4]);
            acc[5] = fmaf(p41.y, vval, acc[5]);
            acc[6] = fmaf(p41.z, vval, acc[6]);
            acc[7] = fmaf(p41.w, vval, acc[7]);
        }
    }

#pragma unroll
    for (int rr = 0; rr < RPW; ++rr) {
        const int row = row0 + w * RPW + rr;
        out[(size_t)row * HD + lane] = acc[rr] / l[rr];
    }
}

extern "C" void kernel_launch(void* const* d_in, const int* in_sizes, int n_in,
                              void* d_out, int out_size, void* d_ws, size_t ws_size,
                              hipStream_t stream) {
    (void)in_sizes; (void)n_in; (void)out_size; (void)d_ws; (void)ws_size;
    const float* x  = (const float*)d_in[0];
    // d_in[1] = mask (int32) — causality computed analytically, unused
    const float* ck = (const float*)d_in[2];
    const float* cv = (const float*)d_in[3];
    const float* Wq = (const float*)d_in[4];
    const float* Wk = (const float*)d_in[5];
    const float* Wv = (const float*)d_in[6];

    float* out  = (float*)d_out;
    float* kout = out + (size_t)NB * TNEW * HD;     // +524288
    float* vout = kout + (size_t)NB * TTOT * HD;    // +2097152
    float* qbuf = out;  // q stored in `out` section; each attn block reads its q rows
                        // into LDS before writing out those same rows — safe aliasing.

    copy_cache<<<dim3(NB * TCACHE * HD / 4 / 256), dim3(256), 0, stream>>>(ck, cv, kout, vout);
    proj<<<dim3(NB * TNEW / PR_ROWS), dim3(256), 0, stream>>>(x, Wq, Wk, Wv, qbuf, kout, vout);
    attn<<<dim3(NB * TNEW / BROWS), dim3(256), 0, stream>>>(qbuf, kout, vout, out);
}

// Round 2
// 108.165 us; speedup vs baseline: 4.8620x; 4.8620x over previous
//
#include <hip/hip_runtime.h>

#define NB     8
#define TNEW   1024
#define TCACHE 3072
#define TTOT   4096
#define EMB    512
#define HD     64

typedef __bf16 bf16x8 __attribute__((ext_vector_type(8)));
typedef __bf16 bf16x4 __attribute__((ext_vector_type(4)));
typedef float  f32x4  __attribute__((ext_vector_type(4)));

#define MFMA(a, b, c) __builtin_amdgcn_mfma_f32_16x16x32_bf16((a), (b), (c), 0, 0, 0)

// ---------- ws layout (bytes) ----------
// Xbf : 0          8192*512*2 = 8388608
// WT  : 8388608    3*64*512*2 = 196608   (WT[m][d][c])
// Qbf : 8585216    8192*64*2  = 1048576
// Kbf : 9633792    8*4096*64*2 = 4194304
// Vtb : 13828096   8*64*4096*2 = 4194304 (per batch: Vt[d][s])
#define WS_XBF 0
#define WS_WT  8388608
#define WS_QBF 8585216
#define WS_KBF 9633792
#define WS_VTB 13828096

// ---------------- k0: x -> bf16 ----------------
__global__ __launch_bounds__(256) void conv_x(const float* __restrict__ x,
                                              __bf16* __restrict__ xb) {
    const int i = blockIdx.x * 256 + threadIdx.x;     // 8 elems each; 524288 total
    const float4* x4 = (const float4*)x;
    const float4 a = x4[i * 2], b = x4[i * 2 + 1];
    bf16x8 o;
    o[0] = (__bf16)a.x; o[1] = (__bf16)a.y; o[2] = (__bf16)a.z; o[3] = (__bf16)a.w;
    o[4] = (__bf16)b.x; o[5] = (__bf16)b.y; o[6] = (__bf16)b.z; o[7] = (__bf16)b.w;
    *(bf16x8*)(xb + (size_t)i * 8) = o;
}

// ---------------- k0b: W -> WT bf16 ----------------
__global__ __launch_bounds__(256) void conv_w(const float* __restrict__ Wq,
                                              const float* __restrict__ Wk,
                                              const float* __restrict__ Wv,
                                              __bf16* __restrict__ wt) {
    const int e = blockIdx.x * 256 + threadIdx.x;     // 3*512*64 = 98304
    const int m = e >> 15;                            // 32768 per matrix
    const int r = e & 32767;
    const int c = r >> 6, d = r & 63;
    const float* W = (m == 0) ? Wq : (m == 1) ? Wk : Wv;
    wt[(size_t)m * HD * EMB + d * EMB + c] = (__bf16)W[c * HD + d];
}

// ---------------- k1: cache copy f32 + bf16 K + bf16 Vt ----------------
__global__ __launch_bounds__(256) void cache_copy(const float* __restrict__ ck,
                                                  const float* __restrict__ cv,
                                                  float* __restrict__ kout,
                                                  float* __restrict__ vout,
                                                  __bf16* __restrict__ kb,
                                                  __bf16* __restrict__ vtb) {
    const int i = blockIdx.x * 256 + threadIdx.x;     // float4 idx, 393216 total
    const int per_b = TCACHE * HD / 4;                // 49152
    const int b = i / per_b;
    const int f = i - b * per_b;
    const int s = f >> 4;
    const int d = (f & 15) * 4;
    const float4 kd = ((const float4*)ck)[i];
    const float4 vd = ((const float4*)cv)[i];
    ((float4*)(kout + (size_t)b * TTOT * HD))[f] = kd;
    ((float4*)(vout + (size_t)b * TTOT * HD))[f] = vd;
    bf16x4 k4; k4[0] = (__bf16)kd.x; k4[1] = (__bf16)kd.y; k4[2] = (__bf16)kd.z; k4[3] = (__bf16)kd.w;
    *(bf16x4*)(kb + (size_t)b * TTOT * HD + s * HD + d) = k4;
    __bf16* vt = vtb + (size_t)b * HD * TTOT;
    vt[(d + 0) * TTOT + s] = (__bf16)vd.x;
    vt[(d + 1) * TTOT + s] = (__bf16)vd.y;
    vt[(d + 2) * TTOT + s] = (__bf16)vd.z;
    vt[(d + 3) * TTOT + s] = (__bf16)vd.w;
}

// ---------------- k2: MFMA projections ----------------
// block = 256 thr (4 waves); wave handles 16 rows x 64 d x 3 matrices
__global__ __launch_bounds__(256, 4) void proj_mfma(const __bf16* __restrict__ xb,
                                                    const __bf16* __restrict__ wt,
                                                    __bf16* __restrict__ qb,
                                                    float* __restrict__ kout,
                                                    float* __restrict__ vout,
                                                    __bf16* __restrict__ kb,
                                                    __bf16* __restrict__ vtb) {
    const int tid = threadIdx.x;
    const int w = tid >> 6, lane = tid & 63;
    const int lo = lane & 15, hi = lane >> 4;
    const int r0 = (blockIdx.x * 4 + w) * 16;         // wave's first row (0..8176)
    const int b = r0 >> 10;

    // A fragments: x[r0+lo][c], 16 chunks of 32
    bf16x8 ax[16];
    const __bf16* xr = xb + (size_t)(r0 + lo) * EMB + hi * 8;
#pragma unroll
    for (int c = 0; c < 16; ++c)
        ax[c] = *(const bf16x8*)(xr + c * 32);

    for (int m = 0; m < 3; ++m) {
        const __bf16* wm = wt + (size_t)m * HD * EMB;
        f32x4 acc[4];
#pragma unroll
        for (int n = 0; n < 4; ++n) acc[n] = (f32x4){0.f, 0.f, 0.f, 0.f};
#pragma unroll
        for (int c = 0; c < 16; ++c) {
#pragma unroll
            for (int n = 0; n < 4; ++n) {
                const bf16x8 bw = *(const bf16x8*)(wm + (size_t)(n * 16 + lo) * EMB + c * 32 + hi * 8);
                acc[n] = MFMA(ax[c], bw, acc[n]);
            }
        }
        // write: row = r0 + hi*4 + rr, col = n*16 + lo
#pragma unroll
        for (int n = 0; n < 4; ++n) {
#pragma unroll
            for (int rr = 0; rr < 4; ++rr) {
                const int grow = r0 + hi * 4 + rr;
                const int t = grow & (TNEW - 1);
                const int d = n * 16 + lo;
                const float val = acc[n][rr];
                if (m == 0) {
                    qb[(size_t)grow * HD + d] = (__bf16)val;
                } else if (m == 1) {
                    const size_t kv = ((size_t)b * TTOT + TCACHE + t) * HD + d;
                    kout[kv] = val;
                    kb[kv] = (__bf16)val;
                } else {
                    const size_t kv = ((size_t)b * TTOT + TCACHE + t) * HD + d;
                    vout[kv] = val;
                    vtb[(size_t)b * HD * TTOT + (size_t)d * TTOT + TCACHE + t] = (__bf16)val;
                }
            }
        }
    }
}

// ---------------- k3: MFMA flash attention, key-split 8 ----------------
#define SW 8   // split waves per block
__global__ __launch_bounds__(512, 4) void attn_mfma(const __bf16* __restrict__ qb,
                                                    const __bf16* __restrict__ kb,
                                                    const __bf16* __restrict__ vtb,
                                                    float* __restrict__ out) {
    __shared__ float cacc[SW][16][64];                 // 32 KB
    __shared__ float cml[SW][16][2];                   // 1 KB
    __shared__ __align__(16) __bf16 P_lds[SW][16][40]; // 10 KB, padded stride

    const int tid = threadIdx.x;
    const int w = tid >> 6, lane = tid & 63;
    const int lo = lane & 15, hi = lane >> 4;

    // XCD swizzle: 512 blocks, 8 XCDs -> contiguous 64-block chunks (= one batch) per XCD
    const int wg = (blockIdx.x & 7) * 64 + (blockIdx.x >> 3);
    const int row0 = wg * 16;
    const int b = row0 >> 10;
    const int t0 = row0 & (TNEW - 1);

    const __bf16* Qb = qb + (size_t)row0 * HD;
    const __bf16* Kb = kb + (size_t)b * TTOT * HD;
    const __bf16* Vt = vtb + (size_t)b * HD * TTOT;

    const bf16x8 aq0 = *(const bf16x8*)(Qb + lo * HD + hi * 8);
    const bf16x8 aq1 = *(const bf16x8*)(Qb + lo * HD + 32 + hi * 8);

    f32x4 o[4];
    float m[4], l[4];
#pragma unroll
    for (int n = 0; n < 4; ++n) o[n] = (f32x4){0.f, 0.f, 0.f, 0.f};
#pragma unroll
    for (int r = 0; r < 4; ++r) { m[r] = -1e30f; l[r] = 0.f; }

    const int ntiles = (TCACHE + t0 + 16 + 31) >> 5;

    for (int tile = w; tile < ntiles; tile += SW) {
        const int s0 = tile << 5;
        // K fragments (B operand = K^T): key = s0 + kg*16 + lo, d chunk
        const bf16x8 bk00 = *(const bf16x8*)(Kb + (size_t)(s0 + lo) * HD + hi * 8);
        const bf16x8 bk01 = *(const bf16x8*)(Kb + (size_t)(s0 + lo) * HD + 32 + hi * 8);
        const bf16x8 bk10 = *(const bf16x8*)(Kb + (size_t)(s0 + 16 + lo) * HD + hi * 8);
        const bf16x8 bk11 = *(const bf16x8*)(Kb + (size_t)(s0 + 16 + lo) * HD + 32 + hi * 8);
        // V fragments for PV (B operand): V[s0 + hi*8+j][n*16+lo] from Vt
        bf16x8 bv[4];
#pragma unroll
        for (int n = 0; n < 4; ++n)
            bv[n] = *(const bf16x8*)(Vt + (size_t)(n * 16 + lo) * TTOT + s0 + hi * 8);

        const f32x4 z = (f32x4){0.f, 0.f, 0.f, 0.f};
        f32x4 sc0 = MFMA(aq0, bk00, z);
        sc0 = MFMA(aq1, bk01, sc0);
        f32x4 sc1 = MFMA(aq0, bk10, z);
        sc1 = MFMA(aq1, bk11, sc1);

        // online softmax; lane holds keys (s0+lo, s0+16+lo) for q rows hi*4+r
        float p0[4], p1[4], corr[4];
#pragma unroll
        for (int r = 0; r < 4; ++r) {
            const int t = t0 + hi * 4 + r;
            const int lim = TCACHE + t;
            const float v0 = (s0 + lo <= lim) ? sc0[r] * 0.125f : -1e30f;
            const float v1 = (s0 + 16 + lo <= lim) ? sc1[r] * 0.125f : -1e30f;
            float mt = fmaxf(v0, v1);
            mt = fmaxf(mt, __shfl_xor(mt, 1));
            mt = fmaxf(mt, __shfl_xor(mt, 2));
            mt = fmaxf(mt, __shfl_xor(mt, 4));
            mt = fmaxf(mt, __shfl_xor(mt, 8));
            const float mn = fmaxf(m[r], mt);
            const float c = __expf(m[r] - mn);
            const float e0 = __expf(v0 - mn);
            const float e1 = __expf(v1 - mn);
            float ps = e0 + e1;
            ps += __shfl_xor(ps, 1);
            ps += __shfl_xor(ps, 2);
            ps += __shfl_xor(ps, 4);
            ps += __shfl_xor(ps, 8);
            l[r] = l[r] * c + ps;
            m[r] = mn;
            corr[r] = c;
            p0[r] = e0;
            p1[r] = e1;
        }
#pragma unroll
        for (int n = 0; n < 4; ++n) {
            o[n][0] *= corr[0]; o[n][1] *= corr[1];
            o[n][2] *= corr[2]; o[n][3] *= corr[3];
        }

        // P transpose through LDS (per-wave private region)
        __bf16* P = &P_lds[w][0][0];
#pragma unroll
        for (int r = 0; r < 4; ++r) {
            P[(hi * 4 + r) * 40 + lo] = (__bf16)p0[r];
            P[(hi * 4 + r) * 40 + 16 + lo] = (__bf16)p1[r];
        }
        asm volatile("" ::: "memory");   // keep ds_writes before the ds_read
        const bf16x8 ap = *(const bf16x8*)(P + lo * 40 + hi * 8);
#pragma unroll
        for (int n = 0; n < 4; ++n)
            o[n] = MFMA(ap, bv[n], o[n]);
    }

    // ---- block combine across the 8 key-splits ----
#pragma unroll
    for (int n = 0; n < 4; ++n)
#pragma unroll
        for (int r = 0; r < 4; ++r)
            cacc[w][hi * 4 + r][n * 16 + lo] = o[n][r];
    if (lo == 0) {
#pragma unroll
        for (int r = 0; r < 4; ++r) {
            cml[w][hi * 4 + r][0] = m[r];
            cml[w][hi * 4 + r][1] = l[r];
        }
    }
    __syncthreads();

    for (int e = tid; e < 16 * 64; e += 512) {
        const int r = e >> 6, d = e & 63;
        float mf = -1e30f;
#pragma unroll
        for (int s = 0; s < SW; ++s) mf = fmaxf(mf, cml[s][r][0]);
        float lf = 0.f, of = 0.f;
#pragma unroll
        for (int s = 0; s < SW; ++s) {
            const float f = __expf(cml[s][r][0] - mf);
            lf += cml[s][r][1] * f;
            of += cacc[s][r][d] * f;
        }
        out[(size_t)(row0 + r) * HD + d] = of / lf;
    }
}

extern "C" void kernel_launch(void* const* d_in, const int* in_sizes, int n_in,
                              void* d_out, int out_size, void* d_ws, size_t ws_size,
                              hipStream_t stream) {
    (void)in_sizes; (void)n_in; (void)out_size; (void)ws_size;
    const float* x  = (const float*)d_in[0];
    const float* ck = (const float*)d_in[2];
    const float* cv = (const float*)d_in[3];
    const float* Wq = (const float*)d_in[4];
    const float* Wk = (const float*)d_in[5];
    const float* Wv = (const float*)d_in[6];

    float* out  = (float*)d_out;
    float* kout = out + (size_t)NB * TNEW * HD;
    float* vout = kout + (size_t)NB * TTOT * HD;

    char* ws = (char*)d_ws;
    __bf16* xb  = (__bf16*)(ws + WS_XBF);
    __bf16* wt  = (__bf16*)(ws + WS_WT);
    __bf16* qb  = (__bf16*)(ws + WS_QBF);
    __bf16* kb  = (__bf16*)(ws + WS_KBF);
    __bf16* vtb = (__bf16*)(ws + WS_VTB);

    conv_x<<<dim3(2048), dim3(256), 0, stream>>>(x, xb);
    conv_w<<<dim3(384), dim3(256), 0, stream>>>(Wq, Wk, Wv, wt);
    cache_copy<<<dim3(1536), dim3(256), 0, stream>>>(ck, cv, kout, vout, kb, vtb);
    proj_mfma<<<dim3(128), dim3(256), 0, stream>>>(xb, wt, qb, kout, vout, kb, vtb);
    attn_mfma<<<dim3(512), dim3(512), 0, stream>>>(qb, kb, vtb, out);
}

// Round 3
// 91.852 us; speedup vs baseline: 5.7254x; 1.1776x over previous
//
#include <hip/hip_runtime.h>

#define NB     8
#define TNEW   1024
#define TCACHE 3072
#define TTOT   4096
#define EMB    512
#define HD     64

typedef __bf16 bf16x8 __attribute__((ext_vector_type(8)));
typedef __bf16 bf16x4 __attribute__((ext_vector_type(4)));
typedef float  f32x4  __attribute__((ext_vector_type(4)));

#define MFMA(a,b,c) __builtin_amdgcn_mfma_f32_16x16x32_bf16((a),(b),(c),0,0,0)

// ---------- ws layout (bytes) ----------
// WT  : 0        3*64*512*2 = 196608   (WT[m][d][c])
// Qbf : 196608   8192*64*2  = 1048576  (q * 0.125, bf16)
// Kbf : 1245184  8*4096*64*2 = 4194304
// Vtb : 5439488  8*64*4096*2 = 4194304 (per batch: Vt[d][s])
#define WS_WT  0
#define WS_QBF 196608
#define WS_KBF 1245184
#define WS_VTB 5439488

// ---------------- k1: fused prep ----------------
// blocks [0,768):    K cache copy + bf16 convert
// blocks [768,1152): V cache copy + bf16 transpose (LDS) -> Vt
// blocks [1152,1536): W transpose -> wt bf16
__global__ __launch_bounds__(256) void prep(const float* __restrict__ ck,
                                            const float* __restrict__ cv,
                                            const float* __restrict__ Wq,
                                            const float* __restrict__ Wk,
                                            const float* __restrict__ Wv,
                                            float* __restrict__ kout,
                                            float* __restrict__ vout,
                                            __bf16* __restrict__ kb,
                                            __bf16* __restrict__ vtb,
                                            __bf16* __restrict__ wt) {
    const int blk = blockIdx.x;
    const int tid = threadIdx.x;
    if (blk < 768) {
        // ---- K: 2 float4 per thread ----
#pragma unroll
        for (int it = 0; it < 2; ++it) {
            const int i = blk * 256 + tid + it * 196608;   // < 393216
            const int b = i / 49152;
            const int f = i - b * 49152;
            const int s = f >> 4, d = (f & 15) * 4;
            const float4 kd = ((const float4*)ck)[i];
            ((float4*)(kout + (size_t)b * TTOT * HD))[f] = kd;
            bf16x4 k4;
            k4[0] = (__bf16)kd.x; k4[1] = (__bf16)kd.y;
            k4[2] = (__bf16)kd.z; k4[3] = (__bf16)kd.w;
            *(bf16x4*)(kb + (size_t)b * TTOT * HD + s * HD + d) = k4;
        }
    } else if (blk < 1152) {
        // ---- V: 64s x 64d tile, transpose through LDS ----
        __shared__ __bf16 vl[64][72];                     // 144B rows (16B aligned)
        const int tb = blk - 768;                         // 0..383
        const int b = tb / 48, si = tb - (tb / 48) * 48;
        const int sbase = si * 64;
        const float4* src = (const float4*)(cv + ((size_t)b * TCACHE + sbase) * HD);
        float4* dstf = (float4*)(vout + ((size_t)b * TTOT + sbase) * HD);
#pragma unroll
        for (int k = 0; k < 4; ++k) {
            const int f = tid + 256 * k;                  // 0..1023
            const int s = f >> 4, d4 = (f & 15) * 4;
            const float4 v = src[f];
            dstf[f] = v;
            bf16x4 t;
            t[0] = (__bf16)v.x; t[1] = (__bf16)v.y;
            t[2] = (__bf16)v.z; t[3] = (__bf16)v.w;
            *(bf16x4*)&vl[s][d4] = t;
        }
        __syncthreads();
        const int d = tid >> 2, sc = tid & 3;
        bf16x8 o0, o1;
#pragma unroll
        for (int i = 0; i < 8; ++i) {
            o0[i] = vl[sc * 16 + i][d];
            o1[i] = vl[sc * 16 + 8 + i][d];
        }
        __bf16* vt = vtb + ((size_t)b * HD + d) * TTOT + sbase + sc * 16;
        *(bf16x8*)vt = o0;
        *(bf16x8*)(vt + 8) = o1;
    } else {
        // ---- W transpose ----
        const int e = (blk - 1152) * 256 + tid;           // < 98304
        const int m = e >> 15;
        const int r = e & 32767;
        const int c = r >> 6, d = r & 63;
        const float* W = (m == 0) ? Wq : (m == 1) ? Wk : Wv;
        wt[(size_t)m * HD * EMB + d * EMB + c] = (__bf16)W[c * HD + d];
    }
}

// ---------------- k2: MFMA projections (1 wave / block, 16 rows) ----------------
__global__ __launch_bounds__(64) void proj_mfma(const float* __restrict__ x,
                                                const __bf16* __restrict__ wt,
                                                __bf16* __restrict__ qb,
                                                float* __restrict__ kout,
                                                float* __restrict__ vout,
                                                __bf16* __restrict__ kb,
                                                __bf16* __restrict__ vtb) {
    __shared__ __bf16 vls[64][24];                        // 48B rows
    const int lane = threadIdx.x;
    const int lo = lane & 15, hi = lane >> 4;
    const int r0 = blockIdx.x * 16;                       // 0..8176
    const int b = r0 >> 10;
    const int t0r = r0 & (TNEW - 1);

    // A fragments from f32 x, converted inline
    bf16x8 ax[16];
    const float* xr = x + (size_t)(r0 + lo) * EMB + hi * 8;
#pragma unroll
    for (int c = 0; c < 16; ++c) {
        const float4 a = *(const float4*)(xr + c * 32);
        const float4 bq = *(const float4*)(xr + c * 32 + 4);
        bf16x8 t;
        t[0] = (__bf16)a.x;  t[1] = (__bf16)a.y;  t[2] = (__bf16)a.z;  t[3] = (__bf16)a.w;
        t[4] = (__bf16)bq.x; t[5] = (__bf16)bq.y; t[6] = (__bf16)bq.z; t[7] = (__bf16)bq.w;
        ax[c] = t;
    }

    for (int m = 0; m < 3; ++m) {
        const __bf16* wm = wt + (size_t)m * HD * EMB;
        f32x4 acc[4];
#pragma unroll
        for (int n = 0; n < 4; ++n) acc[n] = (f32x4){0.f, 0.f, 0.f, 0.f};
#pragma unroll
        for (int c = 0; c < 16; ++c) {
#pragma unroll
            for (int n = 0; n < 4; ++n) {
                const bf16x8 bw = *(const bf16x8*)(wm + (size_t)(n * 16 + lo) * EMB + c * 32 + hi * 8);
                acc[n] = MFMA(ax[c], bw, acc[n]);
            }
        }
#pragma unroll
        for (int n = 0; n < 4; ++n) {
#pragma unroll
            for (int rr = 0; rr < 4; ++rr) {
                const int grow = r0 + hi * 4 + rr;
                const int t = grow & (TNEW - 1);
                const int d = n * 16 + lo;
                const float val = acc[n][rr];
                if (m == 0) {
                    qb[(size_t)grow * HD + d] = (__bf16)(val * 0.125f);
                } else if (m == 1) {
                    const size_t kv = ((size_t)b * TTOT + TCACHE + t) * HD + d;
                    kout[kv] = val;
                    kb[kv] = (__bf16)val;
                } else {
                    const size_t kv = ((size_t)b * TTOT + TCACHE + t) * HD + d;
                    vout[kv] = val;
                    vls[d][hi * 4 + rr] = (__bf16)val;
                }
            }
        }
    }
    __syncthreads();
    // Vt write: lane owns one d row, 16 contiguous t
    bf16x8 v0 = *(const bf16x8*)&vls[lane][0];
    bf16x8 v1 = *(const bf16x8*)&vls[lane][8];
    __bf16* vt = vtb + ((size_t)b * HD + lane) * TTOT + TCACHE + t0r;
    *(bf16x8*)vt = v0;
    *(bf16x8*)(vt + 8) = v1;
}

// ---------------- k3: MFMA flash attention, key-split 8, KT=64 ----------------
#define SW 8
#define DEFER_THR 8.0f
__global__ __launch_bounds__(512, 4) void attn_mfma(const __bf16* __restrict__ qb,
                                                    const __bf16* __restrict__ kb,
                                                    const __bf16* __restrict__ vtb,
                                                    float* __restrict__ out) {
    __shared__ float cacc[SW][16][64];                    // 32 KB
    __shared__ float cml[SW][16][2];                      // 1 KB
    __shared__ __align__(16) __bf16 P_lds[SW][16][72];    // 18 KB

    const int tid = threadIdx.x;
    const int w = tid >> 6, lane = tid & 63;
    const int lo = lane & 15, hi = lane >> 4;

    const int wg = (blockIdx.x & 7) * 64 + (blockIdx.x >> 3);   // XCD swizzle
    const int row0 = wg * 16;
    const int b = row0 >> 10;
    const int t0 = row0 & (TNEW - 1);

    const __bf16* Qb = qb + (size_t)row0 * HD;
    const __bf16* Kb = kb + (size_t)b * TTOT * HD;
    const __bf16* Vt = vtb + (size_t)b * HD * TTOT;
    __bf16* Pw = &P_lds[w][0][0];

    const bf16x8 aq0 = *(const bf16x8*)(Qb + lo * HD + hi * 8);
    const bf16x8 aq1 = *(const bf16x8*)(Qb + lo * HD + 32 + hi * 8);

    f32x4 o[4];
    float m[4], l[4];
#pragma unroll
    for (int n = 0; n < 4; ++n) o[n] = (f32x4){0.f, 0.f, 0.f, 0.f};
#pragma unroll
    for (int r = 0; r < 4; ++r) { m[r] = -1e30f; l[r] = 0.f; }

    const int nt = (TCACHE + t0 + 16 + 63) >> 6;

    for (int tile = w; tile < nt; tile += SW) {
        const int s0 = tile << 6;

        // ---- K fragments + QK^T ----
        const f32x4 z = (f32x4){0.f, 0.f, 0.f, 0.f};
        f32x4 sc[4];
#pragma unroll
        for (int kg = 0; kg < 4; ++kg) {
            const bf16x8 bk0 = *(const bf16x8*)(Kb + (size_t)(s0 + kg * 16 + lo) * HD + hi * 8);
            const bf16x8 bk1 = *(const bf16x8*)(Kb + (size_t)(s0 + kg * 16 + lo) * HD + 32 + hi * 8);
            sc[kg] = MFMA(aq0, bk0, z);
            sc[kg] = MFMA(aq1, bk1, sc[kg]);
        }

        // ---- V fragments (issued early; consumed after softmax) ----
        bf16x8 bv0[4], bv1[4];
#pragma unroll
        for (int n = 0; n < 4; ++n) {
            bv0[n] = *(const bf16x8*)(Vt + (size_t)(n * 16 + lo) * TTOT + s0 + hi * 8);
            bv1[n] = *(const bf16x8*)(Vt + (size_t)(n * 16 + lo) * TTOT + s0 + 32 + hi * 8);
        }

        // ---- mask (wave-uniform branch; only boundary tiles) ----
        if (s0 + 63 > TCACHE + t0) {
#pragma unroll
            for (int rr = 0; rr < 4; ++rr) {
                const int lim = TCACHE + t0 + hi * 4 + rr;
#pragma unroll
                for (int kg = 0; kg < 4; ++kg)
                    if (s0 + kg * 16 + lo > lim) sc[kg][rr] = -1e30f;
            }
        }

        // ---- row max (one tree per row per 64 keys) ----
        float mtr[4];
        bool need = false;
#pragma unroll
        for (int rr = 0; rr < 4; ++rr) {
            float mt = fmaxf(fmaxf(sc[0][rr], sc[1][rr]), fmaxf(sc[2][rr], sc[3][rr]));
            mt = fmaxf(mt, __shfl_xor(mt, 1));
            mt = fmaxf(mt, __shfl_xor(mt, 2));
            mt = fmaxf(mt, __shfl_xor(mt, 4));
            mt = fmaxf(mt, __shfl_xor(mt, 8));
            mtr[rr] = mt;
            need = need || (mt > m[rr] + DEFER_THR);
        }
        if (__any(need)) {   // rescale path (rare after warmup)
#pragma unroll
            for (int rr = 0; rr < 4; ++rr) {
                const float mn = fmaxf(m[rr], mtr[rr]);
                const float corr = __expf(m[rr] - mn);
                l[rr] *= corr;
                m[rr] = mn;
#pragma unroll
                for (int n = 0; n < 4; ++n) o[n][rr] *= corr;
            }
        }

        // ---- exp, row sum, P write ----
#pragma unroll
        for (int rr = 0; rr < 4; ++rr) {
            const float e0 = __expf(sc[0][rr] - m[rr]);
            const float e1 = __expf(sc[1][rr] - m[rr]);
            const float e2 = __expf(sc[2][rr] - m[rr]);
            const float e3 = __expf(sc[3][rr] - m[rr]);
            float ps = (e0 + e1) + (e2 + e3);
            ps += __shfl_xor(ps, 1);
            ps += __shfl_xor(ps, 2);
            ps += __shfl_xor(ps, 4);
            ps += __shfl_xor(ps, 8);
            l[rr] += ps;
            __bf16* pr = Pw + (hi * 4 + rr) * 72;
            pr[lo]      = (__bf16)e0;
            pr[16 + lo] = (__bf16)e1;
            pr[32 + lo] = (__bf16)e2;
            pr[48 + lo] = (__bf16)e3;
        }
        asm volatile("" ::: "memory");

        // ---- PV ----
        const bf16x8 ap0 = *(const bf16x8*)(Pw + lo * 72 + hi * 8);
        const bf16x8 ap1 = *(const bf16x8*)(Pw + lo * 72 + 32 + hi * 8);
#pragma unroll
        for (int n = 0; n < 4; ++n) o[n] = MFMA(ap0, bv0[n], o[n]);
#pragma unroll
        for (int n = 0; n < 4; ++n) o[n] = MFMA(ap1, bv1[n], o[n]);
    }

    // ---- block combine across the 8 key-splits ----
#pragma unroll
    for (int n = 0; n < 4; ++n)
#pragma unroll
        for (int r = 0; r < 4; ++r)
            cacc[w][hi * 4 + r][n * 16 + lo] = o[n][r];
    if (lo == 0) {
#pragma unroll
        for (int r = 0; r < 4; ++r) {
            cml[w][hi * 4 + r][0] = m[r];
            cml[w][hi * 4 + r][1] = l[r];
        }
    }
    __syncthreads();

    for (int e = tid; e < 16 * 64; e += 512) {
        const int r = e >> 6, d = e & 63;
        float mf = -1e30f;
#pragma unroll
        for (int s = 0; s < SW; ++s) mf = fmaxf(mf, cml[s][r][0]);
        float lf = 0.f, of = 0.f;
#pragma unroll
        for (int s = 0; s < SW; ++s) {
            const float f = __expf(cml[s][r][0] - mf);
            lf += cml[s][r][1] * f;
            of += cacc[s][r][d] * f;
        }
        out[(size_t)(row0 + r) * HD + d] = of / lf;
    }
}

extern "C" void kernel_launch(void* const* d_in, const int* in_sizes, int n_in,
                              void* d_out, int out_size, void* d_ws, size_t ws_size,
                              hipStream_t stream) {
    (void)in_sizes; (void)n_in; (void)out_size; (void)ws_size;
    const float* x  = (const float*)d_in[0];
    const float* ck = (const float*)d_in[2];
    const float* cv = (const float*)d_in[3];
    const float* Wq = (const float*)d_in[4];
    const float* Wk = (const float*)d_in[5];
    const float* Wv = (const float*)d_in[6];

    float* out  = (float*)d_out;
    float* kout = out + (size_t)NB * TNEW * HD;
    float* vout = kout + (size_t)NB * TTOT * HD;

    char* ws = (char*)d_ws;
    __bf16* wt  = (__bf16*)(ws + WS_WT);
    __bf16* qb  = (__bf16*)(ws + WS_QBF);
    __bf16* kb  = (__bf16*)(ws + WS_KBF);
    __bf16* vtb = (__bf16*)(ws + WS_VTB);

    prep<<<dim3(1536), dim3(256), 0, stream>>>(ck, cv, Wq, Wk, Wv, kout, vout, kb, vtb, wt);
    proj_mfma<<<dim3(512), dim3(64), 0, stream>>>(x, wt, qb, kout, vout, kb, vtb);
    attn_mfma<<<dim3(512), dim3(512), 0, stream>>>(qb, kb, vtb, out);
}

// Round 4
// 78.918 us; speedup vs baseline: 6.6638x; 1.1639x over previous
//
#include <hip/hip_runtime.h>

#define NB     8
#define TNEW   1024
#define TCACHE 3072
#define TTOT   4096
#define EMB    512
#define HD     64

typedef __bf16 bf16x8 __attribute__((ext_vector_type(8)));
typedef __bf16 bf16x4 __attribute__((ext_vector_type(4)));
typedef float  f32x4  __attribute__((ext_vector_type(4)));

#define MFMA(a,b,c) __builtin_amdgcn_mfma_f32_16x16x32_bf16((a),(b),(c),0,0,0)

#define GLOAD_LDS16(g, l) \
    __builtin_amdgcn_global_load_lds((const __attribute__((address_space(1))) void*)(g), \
                                     (__attribute__((address_space(3))) void*)(l), 16, 0, 0)

// ---------- ws layout (bytes) ----------
// WT    : 0         3*64*512*2 = 196608   (WT[m][d][c])
// Kbf   : 196608    8*4096*64*2 = 4194304
// Vtb   : 4390912   8*64*4096*2 = 4194304 (per batch: Vt[d][s])
// Opart : 8585216   8*8192*64*2 = 8388608 (bf16, [split][row][d])
// mlpart: 16973824  8*8192*2*4  = 524288  (f32, [split][row][{m,l}])
// total = 17498112  (< 18022400 proven available)
#define WS_WT   0
#define WS_KBF  196608
#define WS_VTB  4390912
#define WS_OP   8585216
#define WS_ML   16973824

// qb (bf16 q*0.125, [8192][64]) lives in d_out's `out` section (2MB f32, only
// written by combine at the very end; attn is its only reader). Safe aliasing.

// ---------------- k1: fused prep ----------------
__global__ __launch_bounds__(256) void prep(const float* __restrict__ ck,
                                            const float* __restrict__ cv,
                                            const float* __restrict__ Wq,
                                            const float* __restrict__ Wk,
                                            const float* __restrict__ Wv,
                                            float* __restrict__ kout,
                                            float* __restrict__ vout,
                                            __bf16* __restrict__ kb,
                                            __bf16* __restrict__ vtb,
                                            __bf16* __restrict__ wt) {
    const int blk = blockIdx.x;
    const int tid = threadIdx.x;
    if (blk < 768) {
        // ---- K: 2 float4 per thread ----
#pragma unroll
        for (int it = 0; it < 2; ++it) {
            const int i = blk * 256 + tid + it * 196608;   // < 393216
            const int b = i / 49152;
            const int f = i - b * 49152;
            const int s = f >> 4, d = (f & 15) * 4;
            const float4 kd = ((const float4*)ck)[i];
            ((float4*)(kout + (size_t)b * TTOT * HD))[f] = kd;
            bf16x4 k4;
            k4[0] = (__bf16)kd.x; k4[1] = (__bf16)kd.y;
            k4[2] = (__bf16)kd.z; k4[3] = (__bf16)kd.w;
            *(bf16x4*)(kb + (size_t)b * TTOT * HD + s * HD + d) = k4;
        }
    } else if (blk < 1152) {
        // ---- V: 64s x 64d tile, transpose through LDS ----
        __shared__ __bf16 vl[64][72];
        const int tb = blk - 768;
        const int b = tb / 48, si = tb - (tb / 48) * 48;
        const int sbase = si * 64;
        const float4* src = (const float4*)(cv + ((size_t)b * TCACHE + sbase) * HD);
        float4* dstf = (float4*)(vout + ((size_t)b * TTOT + sbase) * HD);
#pragma unroll
        for (int k = 0; k < 4; ++k) {
            const int f = tid + 256 * k;
            const int s = f >> 4, d4 = (f & 15) * 4;
            const float4 v = src[f];
            dstf[f] = v;
            bf16x4 t;
            t[0] = (__bf16)v.x; t[1] = (__bf16)v.y;
            t[2] = (__bf16)v.z; t[3] = (__bf16)v.w;
            *(bf16x4*)&vl[s][d4] = t;
        }
        __syncthreads();
        const int d = tid >> 2, sc = tid & 3;
        bf16x8 o0, o1;
#pragma unroll
        for (int i = 0; i < 8; ++i) {
            o0[i] = vl[sc * 16 + i][d];
            o1[i] = vl[sc * 16 + 8 + i][d];
        }
        __bf16* vt = vtb + ((size_t)b * HD + d) * TTOT + sbase + sc * 16;
        *(bf16x8*)vt = o0;
        *(bf16x8*)(vt + 8) = o1;
    } else {
        // ---- W transpose ----
        const int e = (blk - 1152) * 256 + tid;
        const int m = e >> 15;
        const int r = e & 32767;
        const int c = r >> 6, d = r & 63;
        const float* W = (m == 0) ? Wq : (m == 1) ? Wk : Wv;
        wt[(size_t)m * HD * EMB + d * EMB + c] = (__bf16)W[c * HD + d];
    }
}

// ---------------- k2: MFMA projections (4 waves/block, 64 rows) ----------------
__global__ __launch_bounds__(256) void proj_mfma(const float* __restrict__ x,
                                                 const __bf16* __restrict__ wt,
                                                 __bf16* __restrict__ qb,
                                                 float* __restrict__ kout,
                                                 float* __restrict__ vout,
                                                 __bf16* __restrict__ kb,
                                                 __bf16* __restrict__ vtb) {
    __shared__ __bf16 vls[4][64][24];
    const int tid = threadIdx.x;
    const int w = tid >> 6, lane = tid & 63;
    const int lo = lane & 15, hi = lane >> 4;
    const int r0 = (blockIdx.x * 4 + w) * 16;
    const int b = r0 >> 10;
    const int t0r = r0 & (TNEW - 1);

    bf16x8 ax[16];
    const float* xr = x + (size_t)(r0 + lo) * EMB + hi * 8;
#pragma unroll
    for (int c = 0; c < 16; ++c) {
        const float4 a = *(const float4*)(xr + c * 32);
        const float4 bq = *(const float4*)(xr + c * 32 + 4);
        bf16x8 t;
        t[0] = (__bf16)a.x;  t[1] = (__bf16)a.y;  t[2] = (__bf16)a.z;  t[3] = (__bf16)a.w;
        t[4] = (__bf16)bq.x; t[5] = (__bf16)bq.y; t[6] = (__bf16)bq.z; t[7] = (__bf16)bq.w;
        ax[c] = t;
    }

    for (int m = 0; m < 3; ++m) {
        const __bf16* wm = wt + (size_t)m * HD * EMB;
        f32x4 acc[4];
#pragma unroll
        for (int n = 0; n < 4; ++n) acc[n] = (f32x4){0.f, 0.f, 0.f, 0.f};
#pragma unroll
        for (int c = 0; c < 16; ++c) {
#pragma unroll
            for (int n = 0; n < 4; ++n) {
                const bf16x8 bw = *(const bf16x8*)(wm + (size_t)(n * 16 + lo) * EMB + c * 32 + hi * 8);
                acc[n] = MFMA(ax[c], bw, acc[n]);
            }
        }
#pragma unroll
        for (int n = 0; n < 4; ++n) {
#pragma unroll
            for (int rr = 0; rr < 4; ++rr) {
                const int grow = r0 + hi * 4 + rr;
                const int t = grow & (TNEW - 1);
                const int d = n * 16 + lo;
                const float val = acc[n][rr];
                if (m == 0) {
                    qb[(size_t)grow * HD + d] = (__bf16)(val * 0.125f);
                } else if (m == 1) {
                    const size_t kv = ((size_t)b * TTOT + TCACHE + t) * HD + d;
                    kout[kv] = val;
                    kb[kv] = (__bf16)val;
                } else {
                    const size_t kv = ((size_t)b * TTOT + TCACHE + t) * HD + d;
                    vout[kv] = val;
                    vls[w][d][hi * 4 + rr] = (__bf16)val;
                }
            }
        }
    }
    __syncthreads();
    bf16x8 v0 = *(const bf16x8*)&vls[w][lane][0];
    bf16x8 v1 = *(const bf16x8*)&vls[w][lane][8];
    __bf16* vt = vtb + ((size_t)b * HD + lane) * TTOT + TCACHE + t0r;
    *(bf16x8*)vt = v0;
    *(bf16x8*)(vt + 8) = v1;
}

// ---------------- k3: flash attention, LDS-shared K/V, key-split 8 ----------------
// grid 256 = 8 batches x 4 qblocks(256 rows) x 8 key-splits(512 keys)
#define QB 256
#define NSPLIT 8
#define SKEYS 512
__global__ __launch_bounds__(512, 2) void attn_mfma(const __bf16* __restrict__ qb,
                                                    const __bf16* __restrict__ kb,
                                                    const __bf16* __restrict__ vtb,
                                                    __bf16* __restrict__ Opart,
                                                    float* __restrict__ mlpart) {
    __shared__ __align__(16) __bf16 Kt[2][64 * 64];      // 8 KB each (swizzled)
    __shared__ __align__(16) __bf16 Vts[2][64 * 64];     // Vt tile [d][s] (swizzled)
    __shared__ __align__(16) __bf16 P_lds[8][16][72];    // 18 KB

    const int tid = threadIdx.x;
    const int wv = tid >> 6, lane = tid & 63;
    const int lo = lane & 15, hi = lane >> 4;

    // XCD swizzle: batch = bid & 7 (one batch's working set per XCD L2)
    const int bid = blockIdx.x;
    const int b = bid & 7;
    const int idx = bid >> 3;              // 0..31
    const int split = idx >> 2;            // 0..7
    const int qloc = idx & 3;              // 0..3
    const int t0 = qloc * QB;              // 0..768
    const int row0 = b * TNEW + t0;        // global q row

    const int s_begin = split * SKEYS;
    int count = ((TCACHE + t0 + QB - s_begin) + 63) >> 6;   // tiles with any valid key
    count = count < 0 ? 0 : (count > 8 ? 8 : count);

    const __bf16* Kb = kb + (size_t)b * TTOT * HD;
    const __bf16* Vb = vtb + (size_t)b * HD * TTOT;

    // staging geometry: wave wv stages rows [wv*8, wv*8+8) of each 64x128B tile,
    // linear LDS dest; source pre-swizzled with byte ^= ((row&7)<<4)
    const int r_st = wv * 8 + (lane >> 3);
    const int c_st = ((lane & 7) * 16) ^ ((lane >> 3) << 4);

    // Q fragments: wave owns 32 rows (2 groups of 16)
    const int t0w = t0 + wv * 32;
    const __bf16* Qw = qb + (size_t)(row0 + wv * 32) * HD;
    bf16x8 aq[2][2];
#pragma unroll
    for (int g = 0; g < 2; ++g) {
        aq[g][0] = *(const bf16x8*)(Qw + (size_t)(g * 16 + lo) * HD + hi * 8);
        aq[g][1] = *(const bf16x8*)(Qw + (size_t)(g * 16 + lo) * HD + 32 + hi * 8);
    }

    f32x4 o[2][4];
    float m[2][4], l[2][4];
#pragma unroll
    for (int g = 0; g < 2; ++g)
#pragma unroll
        for (int n = 0; n < 4; ++n) o[g][n] = (f32x4){0.f, 0.f, 0.f, 0.f};
#pragma unroll
    for (int g = 0; g < 2; ++g)
#pragma unroll
        for (int r = 0; r < 4; ++r) { m[g][r] = -1e30f; l[g][r] = 0.f; }

    if (count > 0) {
        const char* gk = (const char*)Kb + (size_t)(s_begin + r_st) * 128 + c_st;
        const char* gv = (const char*)Vb + ((size_t)r_st * TTOT + s_begin) * 2 + c_st;
        GLOAD_LDS16(gk, Kt[0] + wv * 512);
        GLOAD_LDS16(gv, Vts[0] + wv * 512);
    }
    __syncthreads();

    const int sw = (lo & 7) << 3;   // element-level read swizzle

    for (int it = 0; it < count; ++it) {
        const int s0 = s_begin + it * 64;
        const int buf = it & 1;
        if (it + 1 < count) {   // prefetch next tile into other buffer
            const int sn = s0 + 64;
            const char* gk = (const char*)Kb + (size_t)(sn + r_st) * 128 + c_st;
            const char* gv = (const char*)Vb + ((size_t)r_st * TTOT + sn) * 2 + c_st;
            GLOAD_LDS16(gk, Kt[buf ^ 1] + wv * 512);
            GLOAD_LDS16(gv, Vts[buf ^ 1] + wv * 512);
        }

        const __bf16* Kl = Kt[buf];
        const __bf16* Vl = Vts[buf];

        // K/V fragments (shared by both row-groups)
        bf16x8 bk[4][2], bv[4][2];
#pragma unroll
        for (int kg = 0; kg < 4; ++kg) {
            const int kr = (kg * 16 + lo) * 64;
            bk[kg][0] = *(const bf16x8*)(Kl + kr + ((hi * 8) ^ sw));
            bk[kg][1] = *(const bf16x8*)(Kl + kr + ((32 + hi * 8) ^ sw));
        }
#pragma unroll
        for (int n = 0; n < 4; ++n) {
            const int vr = (n * 16 + lo) * 64;
            bv[n][0] = *(const bf16x8*)(Vl + vr + ((hi * 8) ^ sw));
            bv[n][1] = *(const bf16x8*)(Vl + vr + ((32 + hi * 8) ^ sw));
        }

#pragma unroll
        for (int g = 0; g < 2; ++g) {
            const int tg = t0w + g * 16;
            const f32x4 z = (f32x4){0.f, 0.f, 0.f, 0.f};
            f32x4 sc[4];
#pragma unroll
            for (int kg = 0; kg < 4; ++kg) {
                sc[kg] = MFMA(aq[g][0], bk[kg][0], z);
                sc[kg] = MFMA(aq[g][1], bk[kg][1], sc[kg]);
            }

            if (s0 + 63 > TCACHE + tg) {
#pragma unroll
                for (int rr = 0; rr < 4; ++rr) {
                    const int lim = TCACHE + tg + hi * 4 + rr;
#pragma unroll
                    for (int kg = 0; kg < 4; ++kg)
                        if (s0 + kg * 16 + lo > lim) sc[kg][rr] = -1e30f;
                }
            }

            float mtr[4];
            bool need = false;
#pragma unroll
            for (int rr = 0; rr < 4; ++rr) {
                float mt = fmaxf(fmaxf(sc[0][rr], sc[1][rr]), fmaxf(sc[2][rr], sc[3][rr]));
                mt = fmaxf(mt, __shfl_xor(mt, 1));
                mt = fmaxf(mt, __shfl_xor(mt, 2));
                mt = fmaxf(mt, __shfl_xor(mt, 4));
                mt = fmaxf(mt, __shfl_xor(mt, 8));
                mtr[rr] = mt;
                need = need || (mt > m[g][rr] + 8.0f);
            }
            if (__any(need)) {
#pragma unroll
                for (int rr = 0; rr < 4; ++rr) {
                    const float mn = fmaxf(m[g][rr], mtr[rr]);
                    const float corr = __expf(m[g][rr] - mn);
                    l[g][rr] *= corr;
                    m[g][rr] = mn;
#pragma unroll
                    for (int n = 0; n < 4; ++n) o[g][n][rr] *= corr;
                }
            }

            __bf16* Pw = &P_lds[wv][0][0];
#pragma unroll
            for (int rr = 0; rr < 4; ++rr) {
                const float e0 = __expf(sc[0][rr] - m[g][rr]);
                const float e1 = __expf(sc[1][rr] - m[g][rr]);
                const float e2 = __expf(sc[2][rr] - m[g][rr]);
                const float e3 = __expf(sc[3][rr] - m[g][rr]);
                float ps = (e0 + e1) + (e2 + e3);
                ps += __shfl_xor(ps, 1);
                ps += __shfl_xor(ps, 2);
                ps += __shfl_xor(ps, 4);
                ps += __shfl_xor(ps, 8);
                l[g][rr] += ps;
                __bf16* pr = Pw + (hi * 4 + rr) * 72;
                pr[lo]      = (__bf16)e0;
                pr[16 + lo] = (__bf16)e1;
                pr[32 + lo] = (__bf16)e2;
                pr[48 + lo] = (__bf16)e3;
            }
            asm volatile("" ::: "memory");

            const bf16x8 ap0 = *(const bf16x8*)(Pw + lo * 72 + hi * 8);
            const bf16x8 ap1 = *(const bf16x8*)(Pw + lo * 72 + 32 + hi * 8);
#pragma unroll
            for (int n = 0; n < 4; ++n) o[g][n] = MFMA(ap0, bv[n][0], o[g][n]);
#pragma unroll
            for (int n = 0; n < 4; ++n) o[g][n] = MFMA(ap1, bv[n][1], o[g][n]);
        }
        __syncthreads();   // all waves done with buf; prefetched buf^1 complete
    }

    // ---- write partials ----
    __bf16* Ow = Opart + ((size_t)split * (NB * TNEW) + row0 + wv * 32) * HD;
#pragma unroll
    for (int g = 0; g < 2; ++g)
#pragma unroll
        for (int n = 0; n < 4; ++n)
#pragma unroll
            for (int rr = 0; rr < 4; ++rr)
                Ow[(size_t)(g * 16 + hi * 4 + rr) * HD + n * 16 + lo] = (__bf16)o[g][n][rr];
    if (lo == 0) {
        float* mlw = mlpart + ((size_t)split * (NB * TNEW) + row0 + wv * 32) * 2;
#pragma unroll
        for (int g = 0; g < 2; ++g)
#pragma unroll
            for (int rr = 0; rr < 4; ++rr) {
                mlw[(g * 16 + hi * 4 + rr) * 2]     = m[g][rr];
                mlw[(g * 16 + hi * 4 + rr) * 2 + 1] = l[g][rr];
            }
    }
}

// ---------------- k4: combine key-split partials ----------------
__global__ __launch_bounds__(256) void combine(const __bf16* __restrict__ Opart,
                                               const float* __restrict__ mlpart,
                                               float* __restrict__ out) {
    const int e = blockIdx.x * 256 + threadIdx.x;   // 524288
    const int row = e >> 6, d = e & 63;
    float mf = -1e30f;
#pragma unroll
    for (int s = 0; s < NSPLIT; ++s)
        mf = fmaxf(mf, mlpart[((size_t)s * (NB * TNEW) + row) * 2]);
    float lf = 0.f, acc = 0.f;
#pragma unroll
    for (int s = 0; s < NSPLIT; ++s) {
        const float ms = mlpart[((size_t)s * (NB * TNEW) + row) * 2];
        const float ls = mlpart[((size_t)s * (NB * TNEW) + row) * 2 + 1];
        const float f = __expf(ms - mf);
        lf += ls * f;
        acc += (float)Opart[((size_t)s * (NB * TNEW) + row) * HD + d] * f;
    }
    out[e] = acc / lf;
}

extern "C" void kernel_launch(void* const* d_in, const int* in_sizes, int n_in,
                              void* d_out, int out_size, void* d_ws, size_t ws_size,
                              hipStream_t stream) {
    (void)in_sizes; (void)n_in; (void)out_size; (void)ws_size;
    const float* x  = (const float*)d_in[0];
    const float* ck = (const float*)d_in[2];
    const float* cv = (const float*)d_in[3];
    const float* Wq = (const float*)d_in[4];
    const float* Wk = (const float*)d_in[5];
    const float* Wv = (const float*)d_in[6];

    float* out  = (float*)d_out;
    float* kout = out + (size_t)NB * TNEW * HD;
    float* vout = kout + (size_t)NB * TTOT * HD;

    char* ws = (char*)d_ws;
    __bf16* wt  = (__bf16*)(ws + WS_WT);
    __bf16* kbf = (__bf16*)(ws + WS_KBF);
    __bf16* vtb = (__bf16*)(ws + WS_VTB);
    __bf16* Op  = (__bf16*)(ws + WS_OP);
    float*  ml  = (float*)(ws + WS_ML);
    __bf16* qb  = (__bf16*)d_out;   // q (bf16) aliases out-section; combine overwrites last

    prep<<<dim3(1536), dim3(256), 0, stream>>>(ck, cv, Wq, Wk, Wv, kout, vout, kbf, vtb, wt);
    proj_mfma<<<dim3(128), dim3(256), 0, stream>>>(x, wt, qb, kout, vout, kbf, vtb);
    attn_mfma<<<dim3(256), dim3(512), 0, stream>>>(qb, kbf, vtb, Op, ml);
    combine<<<dim3(2048), dim3(256), 0, stream>>>(Op, ml, out);
}

// Round 5
// 71.380 us; speedup vs baseline: 7.3676x; 1.1056x over previous
//
#include <hip/hip_runtime.h>

#define NB     8
#define TNEW   1024
#define TCACHE 3072
#define TTOT   4096
#define EMB    512
#define HD     64

typedef __bf16 bf16x8 __attribute__((ext_vector_type(8)));
typedef __bf16 bf16x4 __attribute__((ext_vector_type(4)));
typedef float  f32x4  __attribute__((ext_vector_type(4)));

#define MFMA(a,b,c) __builtin_amdgcn_mfma_f32_16x16x32_bf16((a),(b),(c),0,0,0)

#define GLOAD_LDS16(g, l) \
    __builtin_amdgcn_global_load_lds((const __attribute__((address_space(1))) void*)(g), \
                                     (__attribute__((address_space(3))) void*)(l), 16, 0, 0)

// log2-domain scale: 1/sqrt(64) * 1/ln(2)
#define QSCALE 0.180336880f

// ---------- ws layout (bytes) ----------
#define WS_WT   0          // 3*64*512*2 = 196608   WT[m][d][c] bf16
#define WS_KBF  196608     // 8*4096*64*2 = 4194304
#define WS_VTB  4390912    // 8*64*4096*2 = 4194304 (per batch: Vt[d][s])
#define WS_OP   8585216    // 8*8192*64*2 = 8388608 (bf16 [split][row][d])
#define WS_ML   16973824   // 8*8192*2*4  = 524288  (f32 [split][row][{m,l}], log2 domain)

// qb (bf16 q*QSCALE, [8192][64]) aliases d_out's out section (written last by combine).

// ---------------- k1: fused prep ----------------
// [0,768): K copy+cvt   [768,1152): V copy + LDS-transpose -> Vt   [1152,1176): W LDS-transpose
__global__ __launch_bounds__(256) void prep(const float* __restrict__ ck,
                                            const float* __restrict__ cv,
                                            const float* __restrict__ Wq,
                                            const float* __restrict__ Wk,
                                            const float* __restrict__ Wv,
                                            float* __restrict__ kout,
                                            float* __restrict__ vout,
                                            __bf16* __restrict__ kb,
                                            __bf16* __restrict__ vtb,
                                            __bf16* __restrict__ wt) {
    const int blk = blockIdx.x;
    const int tid = threadIdx.x;
    if (blk < 768) {
#pragma unroll
        for (int it = 0; it < 2; ++it) {
            const int i = blk * 256 + tid + it * 196608;
            const int b = i / 49152;
            const int f = i - b * 49152;
            const int s = f >> 4, d = (f & 15) * 4;
            const float4 kd = ((const float4*)ck)[i];
            ((float4*)(kout + (size_t)b * TTOT * HD))[f] = kd;
            bf16x4 k4;
            k4[0] = (__bf16)kd.x; k4[1] = (__bf16)kd.y;
            k4[2] = (__bf16)kd.z; k4[3] = (__bf16)kd.w;
            *(bf16x4*)(kb + (size_t)b * TTOT * HD + s * HD + d) = k4;
        }
    } else if (blk < 1152) {
        __shared__ __bf16 vl[64][72];
        const int tb = blk - 768;
        const int b = tb / 48, si = tb - (tb / 48) * 48;
        const int sbase = si * 64;
        const float4* src = (const float4*)(cv + ((size_t)b * TCACHE + sbase) * HD);
        float4* dstf = (float4*)(vout + ((size_t)b * TTOT + sbase) * HD);
#pragma unroll
        for (int k = 0; k < 4; ++k) {
            const int f = tid + 256 * k;
            const int s = f >> 4, d4 = (f & 15) * 4;
            const float4 v = src[f];
            dstf[f] = v;
            bf16x4 t;
            t[0] = (__bf16)v.x; t[1] = (__bf16)v.y;
            t[2] = (__bf16)v.z; t[3] = (__bf16)v.w;
            *(bf16x4*)&vl[s][d4] = t;
        }
        __syncthreads();
        const int d = tid >> 2, sc = tid & 3;
        bf16x8 o0, o1;
#pragma unroll
        for (int i = 0; i < 8; ++i) {
            o0[i] = vl[sc * 16 + i][d];
            o1[i] = vl[sc * 16 + 8 + i][d];
        }
        __bf16* vt = vtb + ((size_t)b * HD + d) * TTOT + sbase + sc * 16;
        *(bf16x8*)vt = o0;
        *(bf16x8*)(vt + 8) = o1;
    } else {
        // ---- W: 64c x 64d tile transpose through LDS, coalesced wt writes ----
        __shared__ __bf16 vl[64][72];
        const int tb = blk - 1152;                 // 0..23
        const int m = tb >> 3;
        const int ct = (tb & 7) * 64;
        const float* W = (m == 0) ? Wq : (m == 1) ? Wk : Wv;
        const float4* src = (const float4*)(W + (size_t)ct * HD);
#pragma unroll
        for (int k = 0; k < 4; ++k) {
            const int f = tid + 256 * k;           // 0..1023
            const int c = f >> 4, d4 = (f & 15) * 4;
            const float4 v = src[f];
            bf16x4 t;
            t[0] = (__bf16)v.x; t[1] = (__bf16)v.y;
            t[2] = (__bf16)v.z; t[3] = (__bf16)v.w;
            *(bf16x4*)&vl[c][d4] = t;
        }
        __syncthreads();
        const int d = tid >> 2, sc = tid & 3;
        bf16x8 o0, o1;
#pragma unroll
        for (int i = 0; i < 8; ++i) {
            o0[i] = vl[sc * 16 + i][d];
            o1[i] = vl[sc * 16 + 8 + i][d];
        }
        __bf16* wr = wt + (size_t)m * HD * EMB + (size_t)d * EMB + ct + sc * 16;
        *(bf16x8*)wr = o0;
        *(bf16x8*)(wr + 8) = o1;
    }
}

// ---------------- k2: MFMA projections (4 waves/block, 64 rows, LDS-staged x) ----------------
__global__ __launch_bounds__(256) void proj_mfma(const float* __restrict__ x,
                                                 const __bf16* __restrict__ wt,
                                                 __bf16* __restrict__ qb,
                                                 float* __restrict__ kout,
                                                 float* __restrict__ vout,
                                                 __bf16* __restrict__ kb,
                                                 __bf16* __restrict__ vtb) {
    __shared__ __bf16 xs[64][520];                 // 66.6 KB, 2-way-free bank stride
    __shared__ __bf16 vls[4][64][24];              // 12 KB
    const int tid = threadIdx.x;
    const int w = tid >> 6, lane = tid & 63;
    const int lo = lane & 15, hi = lane >> 4;
    const int r0 = (blockIdx.x * 4 + w) * 16;
    const int b = r0 >> 10;
    const int t0r = r0 & (TNEW - 1);

    // stage 64x512 f32 -> bf16 LDS (coalesced)
    {
        const float4* xg = (const float4*)(x + (size_t)blockIdx.x * 64 * EMB);
#pragma unroll
        for (int k = 0; k < 32; ++k) {
            const int f = tid + 256 * k;           // 0..8191
            const int row = f >> 7, col4 = (f & 127) * 4;
            const float4 v = xg[f];
            bf16x4 t;
            t[0] = (__bf16)v.x; t[1] = (__bf16)v.y;
            t[2] = (__bf16)v.z; t[3] = (__bf16)v.w;
            *(bf16x4*)&xs[row][col4] = t;
        }
    }
    __syncthreads();

    for (int m = 0; m < 3; ++m) {
        const __bf16* wm = wt + (size_t)m * HD * EMB;
        f32x4 acc[4];
#pragma unroll
        for (int n = 0; n < 4; ++n) acc[n] = (f32x4){0.f, 0.f, 0.f, 0.f};
#pragma unroll
        for (int c = 0; c < 16; ++c) {
            const bf16x8 ax = *(const bf16x8*)&xs[w * 16 + lo][c * 32 + hi * 8];
#pragma unroll
            for (int n = 0; n < 4; ++n) {
                const bf16x8 bw = *(const bf16x8*)(wm + (size_t)(n * 16 + lo) * EMB + c * 32 + hi * 8);
                acc[n] = MFMA(ax, bw, acc[n]);
            }
        }
#pragma unroll
        for (int n = 0; n < 4; ++n) {
#pragma unroll
            for (int rr = 0; rr < 4; ++rr) {
                const int grow = r0 + hi * 4 + rr;
                const int t = grow & (TNEW - 1);
                const int d = n * 16 + lo;
                const float val = acc[n][rr];
                if (m == 0) {
                    qb[(size_t)grow * HD + d] = (__bf16)(val * QSCALE);
                } else if (m == 1) {
                    const size_t kv = ((size_t)b * TTOT + TCACHE + t) * HD + d;
                    kout[kv] = val;
                    kb[kv] = (__bf16)val;
                } else {
                    const size_t kv = ((size_t)b * TTOT + TCACHE + t) * HD + d;
                    vout[kv] = val;
                    vls[w][d][hi * 4 + rr] = (__bf16)val;
                }
            }
        }
    }
    __syncthreads();
    bf16x8 v0 = *(const bf16x8*)&vls[w][lane][0];
    bf16x8 v1 = *(const bf16x8*)&vls[w][lane][8];
    __bf16* vt = vtb + ((size_t)b * HD + lane) * TTOT + TCACHE + t0r;
    *(bf16x8*)vt = v0;
    *(bf16x8*)(vt + 8) = v1;
}

// ---------------- k3: flash attention, LDS-shared K/V, QB=128, split 8 ----------------
// grid 512 = 8 batches x 8 qblocks(128 rows) x 8 key-splits(512 keys); 2 blocks/CU
#define QB 128
#define NSPLIT 8
#define SKEYS 512
__global__ __launch_bounds__(512, 2) void attn_mfma(const __bf16* __restrict__ qb,
                                                    const __bf16* __restrict__ kb,
                                                    const __bf16* __restrict__ vtb,
                                                    __bf16* __restrict__ Opart,
                                                    float* __restrict__ mlpart) {
    __shared__ __align__(16) __bf16 Kt[2][64 * 64];
    __shared__ __align__(16) __bf16 Vts[2][64 * 64];
    __shared__ __align__(16) __bf16 P_lds[8][16][72];

    const int tid = threadIdx.x;
    const int wv = tid >> 6, lane = tid & 63;
    const int lo = lane & 15, hi = lane >> 4;

    const int bid = blockIdx.x;
    const int b = bid & 7;                 // XCD-major: one batch per XCD
    const int idx = bid >> 3;              // 0..63
    const int split = idx & 7;
    const int qloc = idx >> 3;             // 0..7
    const int t0 = qloc * QB;
    const int row0 = b * TNEW + t0;

    const int s_begin = split * SKEYS;
    int count = ((TCACHE + t0 + QB - s_begin) + 63) >> 6;
    count = count < 0 ? 0 : (count > 8 ? 8 : count);

    const __bf16* Kb = kb + (size_t)b * TTOT * HD;
    const __bf16* Vb = vtb + (size_t)b * HD * TTOT;

    const int r_st = wv * 8 + (lane >> 3);
    const int c_st = ((lane & 7) * 16) ^ ((lane >> 3) << 4);

    const int t0w = t0 + wv * 16;
    const __bf16* Qw = qb + (size_t)(row0 + wv * 16) * HD;
    const bf16x8 aq0 = *(const bf16x8*)(Qw + (size_t)lo * HD + hi * 8);
    const bf16x8 aq1 = *(const bf16x8*)(Qw + (size_t)lo * HD + 32 + hi * 8);

    f32x4 o[4];
    float m[4], l[4];
#pragma unroll
    for (int n = 0; n < 4; ++n) o[n] = (f32x4){0.f, 0.f, 0.f, 0.f};
#pragma unroll
    for (int r = 0; r < 4; ++r) { m[r] = -1e30f; l[r] = 0.f; }

    if (count > 0) {
        const char* gk = (const char*)Kb + (size_t)(s_begin + r_st) * 128 + c_st;
        const char* gv = (const char*)Vb + ((size_t)r_st * TTOT + s_begin) * 2 + c_st;
        GLOAD_LDS16(gk, Kt[0] + wv * 512);
        GLOAD_LDS16(gv, Vts[0] + wv * 512);
    }
    __syncthreads();

    const int sw = (lo & 7) << 3;

    for (int it = 0; it < count; ++it) {
        const int s0 = s_begin + it * 64;
        const int buf = it & 1;
        if (it + 1 < count) {
            const int sn = s0 + 64;
            const char* gk = (const char*)Kb + (size_t)(sn + r_st) * 128 + c_st;
            const char* gv = (const char*)Vb + ((size_t)r_st * TTOT + sn) * 2 + c_st;
            GLOAD_LDS16(gk, Kt[buf ^ 1] + wv * 512);
            GLOAD_LDS16(gv, Vts[buf ^ 1] + wv * 512);
        }

        const __bf16* Kl = Kt[buf];
        const __bf16* Vl = Vts[buf];

        bf16x8 bk[4][2], bv[4][2];
#pragma unroll
        for (int kg = 0; kg < 4; ++kg) {
            const int kr = (kg * 16 + lo) * 64;
            bk[kg][0] = *(const bf16x8*)(Kl + kr + ((hi * 8) ^ sw));
            bk[kg][1] = *(const bf16x8*)(Kl + kr + ((32 + hi * 8) ^ sw));
        }
#pragma unroll
        for (int n = 0; n < 4; ++n) {
            const int vr = (n * 16 + lo) * 64;
            bv[n][0] = *(const bf16x8*)(Vl + vr + ((hi * 8) ^ sw));
            bv[n][1] = *(const bf16x8*)(Vl + vr + ((32 + hi * 8) ^ sw));
        }

        const f32x4 z = (f32x4){0.f, 0.f, 0.f, 0.f};
        f32x4 sc[4];
#pragma unroll
        for (int kg = 0; kg < 4; ++kg) {
            sc[kg] = MFMA(aq0, bk[kg][0], z);
            sc[kg] = MFMA(aq1, bk[kg][1], sc[kg]);
        }

        if (s0 + 63 > TCACHE + t0w) {
#pragma unroll
            for (int rr = 0; rr < 4; ++rr) {
                const int lim = TCACHE + t0w + hi * 4 + rr;
#pragma unroll
                for (int kg = 0; kg < 4; ++kg)
                    if (s0 + kg * 16 + lo > lim) sc[kg][rr] = -1e30f;
            }
        }

        float mtr[4];
        bool need = false;
#pragma unroll
        for (int rr = 0; rr < 4; ++rr) {
            float mt = fmaxf(fmaxf(sc[0][rr], sc[1][rr]), fmaxf(sc[2][rr], sc[3][rr]));
            mt = fmaxf(mt, __shfl_xor(mt, 1));
            mt = fmaxf(mt, __shfl_xor(mt, 2));
            mt = fmaxf(mt, __shfl_xor(mt, 4));
            mt = fmaxf(mt, __shfl_xor(mt, 8));
            mtr[rr] = mt;
            need = need || (mt > m[rr] + 8.0f);
        }
        if (__any(need)) {
#pragma unroll
            for (int rr = 0; rr < 4; ++rr) {
                const float mn = fmaxf(m[rr], mtr[rr]);
                const float corr = exp2f(m[rr] - mn);
                l[rr] *= corr;
                m[rr] = mn;
#pragma unroll
                for (int n = 0; n < 4; ++n) o[n][rr] *= corr;
            }
        }

        __bf16* Pw = &P_lds[wv][0][0];
#pragma unroll
        for (int rr = 0; rr < 4; ++rr) {
            const float e0 = exp2f(sc[0][rr] - m[rr]);
            const float e1 = exp2f(sc[1][rr] - m[rr]);
            const float e2 = exp2f(sc[2][rr] - m[rr]);
            const float e3 = exp2f(sc[3][rr] - m[rr]);
            float ps = (e0 + e1) + (e2 + e3);
            ps += __shfl_xor(ps, 1);
            ps += __shfl_xor(ps, 2);
            ps += __shfl_xor(ps, 4);
            ps += __shfl_xor(ps, 8);
            l[rr] += ps;
            __bf16* pr = Pw + (hi * 4 + rr) * 72;
            pr[lo]      = (__bf16)e0;
            pr[16 + lo] = (__bf16)e1;
            pr[32 + lo] = (__bf16)e2;
            pr[48 + lo] = (__bf16)e3;
        }
        asm volatile("" ::: "memory");

        const bf16x8 ap0 = *(const bf16x8*)(Pw + lo * 72 + hi * 8);
        const bf16x8 ap1 = *(const bf16x8*)(Pw + lo * 72 + 32 + hi * 8);
#pragma unroll
        for (int n = 0; n < 4; ++n) o[n] = MFMA(ap0, bv[n][0], o[n]);
#pragma unroll
        for (int n = 0; n < 4; ++n) o[n] = MFMA(ap1, bv[n][1], o[n]);

        __syncthreads();
    }

    __bf16* Ow = Opart + ((size_t)split * (NB * TNEW) + row0 + wv * 16) * HD;
#pragma unroll
    for (int n = 0; n < 4; ++n)
#pragma unroll
        for (int rr = 0; rr < 4; ++rr)
            Ow[(size_t)(hi * 4 + rr) * HD + n * 16 + lo] = (__bf16)o[n][rr];
    if (lo == 0) {
        float* mlw = mlpart + ((size_t)split * (NB * TNEW) + row0 + wv * 16) * 2;
#pragma unroll
        for (int rr = 0; rr < 4; ++rr) {
            mlw[(hi * 4 + rr) * 2]     = m[rr];
            mlw[(hi * 4 + rr) * 2 + 1] = l[rr];
        }
    }
}

// ---------------- k4: combine key-split partials ----------------
__global__ __launch_bounds__(256) void combine(const __bf16* __restrict__ Opart,
                                               const float* __restrict__ mlpart,
                                               float* __restrict__ out) {
    const int e = blockIdx.x * 256 + threadIdx.x;
    const int row = e >> 6, d = e & 63;
    float mf = -1e30f;
#pragma unroll
    for (int s = 0; s < NSPLIT; ++s)
        mf = fmaxf(mf, mlpart[((size_t)s * (NB * TNEW) + row) * 2]);
    float lf = 0.f, acc = 0.f;
#pragma unroll
    for (int s = 0; s < NSPLIT; ++s) {
        const float ms = mlpart[((size_t)s * (NB * TNEW) + row) * 2];
        const float ls = mlpart[((size_t)s * (NB * TNEW) + row) * 2 + 1];
        const float f = exp2f(ms - mf);
        lf += ls * f;
        acc += (float)Opart[((size_t)s * (NB * TNEW) + row) * HD + d] * f;
    }
    out[e] = acc / lf;
}

extern "C" void kernel_launch(void* const* d_in, const int* in_sizes, int n_in,
                              void* d_out, int out_size, void* d_ws, size_t ws_size,
                              hipStream_t stream) {
    (void)in_sizes; (void)n_in; (void)out_size; (void)ws_size;
    const float* x  = (const float*)d_in[0];
    const float* ck = (const float*)d_in[2];
    const float* cv = (const float*)d_in[3];
    const float* Wq = (const float*)d_in[4];
    const float* Wk = (const float*)d_in[5];
    const float* Wv = (const float*)d_in[6];

    float* out  = (float*)d_out;
    float* kout = out + (size_t)NB * TNEW * HD;
    float* vout = kout + (size_t)NB * TTOT * HD;

    char* ws = (char*)d_ws;
    __bf16* wt  = (__bf16*)(ws + WS_WT);
    __bf16* kbf = (__bf16*)(ws + WS_KBF);
    __bf16* vtb = (__bf16*)(ws + WS_VTB);
    __bf16* Op  = (__bf16*)(ws + WS_OP);
    float*  ml  = (float*)(ws + WS_ML);
    __bf16* qb  = (__bf16*)d_out;

    prep<<<dim3(1176), dim3(256), 0, stream>>>(ck, cv, Wq, Wk, Wv, kout, vout, kbf, vtb, wt);
    proj_mfma<<<dim3(128), dim3(256), 0, stream>>>(x, wt, qb, kout, vout, kbf, vtb);
    attn_mfma<<<dim3(512), dim3(512), 0, stream>>>(qb, kbf, vtb, Op, ml);
    combine<<<dim3(2048), dim3(256), 0, stream>>>(Op, ml, out);
}

// Round 6
// 65.062 us; speedup vs baseline: 8.0830x; 1.0971x over previous
//
#include <hip/hip_runtime.h>

#define NB     8
#define TNEW   1024
#define TCACHE 3072
#define TTOT   4096
#define EMB    512
#define HD     64

typedef __bf16 bf16x8 __attribute__((ext_vector_type(8)));
typedef __bf16 bf16x4 __attribute__((ext_vector_type(4)));
typedef float  f32x4  __attribute__((ext_vector_type(4)));

#define MFMA(a,b,c) __builtin_amdgcn_mfma_f32_16x16x32_bf16((a),(b),(c),0,0,0)

#define GLOAD_LDS16(g, l) \
    __builtin_amdgcn_global_load_lds((const __attribute__((address_space(1))) void*)(g), \
                                     (__attribute__((address_space(3))) void*)(l), 16, 0, 0)

// log2-domain scale: 1/sqrt(64) * 1/ln(2)
#define QSCALE 0.180336880f

// ---------- ws layout (bytes) ----------
#define WS_WT   0          // 3*64*512*2 = 196608   WT[m][d][c] bf16
#define WS_KBF  196608     // 8*4096*64*2 = 4194304
#define WS_VTB  4390912    // 8*64*4096*2 = 4194304 (per batch: Vt[d][s])
#define WS_OP   8585216    // 8*8192*64*2 = 8388608 (bf16 [split][row][d])
#define WS_ML   16973824   // 8*8192*2*4  = 524288  (f32 [split][row][{m,l}], log2 domain)

// qb (bf16 q*QSCALE, [8192][64]) aliases d_out's out section (written last by combine).

// ---------------- k1: fused prep ----------------
__global__ __launch_bounds__(256) void prep(const float* __restrict__ ck,
                                            const float* __restrict__ cv,
                                            const float* __restrict__ Wq,
                                            const float* __restrict__ Wk,
                                            const float* __restrict__ Wv,
                                            float* __restrict__ kout,
                                            float* __restrict__ vout,
                                            __bf16* __restrict__ kb,
                                            __bf16* __restrict__ vtb,
                                            __bf16* __restrict__ wt) {
    const int blk = blockIdx.x;
    const int tid = threadIdx.x;
    if (blk < 768) {
#pragma unroll
        for (int it = 0; it < 2; ++it) {
            const int i = blk * 256 + tid + it * 196608;
            const int b = i / 49152;
            const int f = i - b * 49152;
            const int s = f >> 4, d = (f & 15) * 4;
            const float4 kd = ((const float4*)ck)[i];
            ((float4*)(kout + (size_t)b * TTOT * HD))[f] = kd;
            bf16x4 k4;
            k4[0] = (__bf16)kd.x; k4[1] = (__bf16)kd.y;
            k4[2] = (__bf16)kd.z; k4[3] = (__bf16)kd.w;
            *(bf16x4*)(kb + (size_t)b * TTOT * HD + s * HD + d) = k4;
        }
    } else if (blk < 1152) {
        __shared__ __bf16 vl[64][72];
        const int tb = blk - 768;
        const int b = tb / 48, si = tb - (tb / 48) * 48;
        const int sbase = si * 64;
        const float4* src = (const float4*)(cv + ((size_t)b * TCACHE + sbase) * HD);
        float4* dstf = (float4*)(vout + ((size_t)b * TTOT + sbase) * HD);
#pragma unroll
        for (int k = 0; k < 4; ++k) {
            const int f = tid + 256 * k;
            const int s = f >> 4, d4 = (f & 15) * 4;
            const float4 v = src[f];
            dstf[f] = v;
            bf16x4 t;
            t[0] = (__bf16)v.x; t[1] = (__bf16)v.y;
            t[2] = (__bf16)v.z; t[3] = (__bf16)v.w;
            *(bf16x4*)&vl[s][d4] = t;
        }
        __syncthreads();
        const int d = tid >> 2, sc = tid & 3;
        bf16x8 o0, o1;
#pragma unroll
        for (int i = 0; i < 8; ++i) {
            o0[i] = vl[sc * 16 + i][d];
            o1[i] = vl[sc * 16 + 8 + i][d];
        }
        __bf16* vt = vtb + ((size_t)b * HD + d) * TTOT + sbase + sc * 16;
        *(bf16x8*)vt = o0;
        *(bf16x8*)(vt + 8) = o1;
    } else {
        __shared__ __bf16 vl[64][72];
        const int tb = blk - 1152;                 // 0..23
        const int m = tb >> 3;
        const int ct = (tb & 7) * 64;
        const float* W = (m == 0) ? Wq : (m == 1) ? Wk : Wv;
        const float4* src = (const float4*)(W + (size_t)ct * HD);
#pragma unroll
        for (int k = 0; k < 4; ++k) {
            const int f = tid + 256 * k;
            const int c = f >> 4, d4 = (f & 15) * 4;
            const float4 v = src[f];
            bf16x4 t;
            t[0] = (__bf16)v.x; t[1] = (__bf16)v.y;
            t[2] = (__bf16)v.z; t[3] = (__bf16)v.w;
            *(bf16x4*)&vl[c][d4] = t;
        }
        __syncthreads();
        const int d = tid >> 2, sc = tid & 3;
        bf16x8 o0, o1;
#pragma unroll
        for (int i = 0; i < 8; ++i) {
            o0[i] = vl[sc * 16 + i][d];
            o1[i] = vl[sc * 16 + 8 + i][d];
        }
        __bf16* wr = wt + (size_t)m * HD * EMB + (size_t)d * EMB + ct + sc * 16;
        *(bf16x8*)wr = o0;
        *(bf16x8*)(wr + 8) = o1;
    }
}

// ---------------- k2: MFMA projections (4 waves/block, 64 rows, LDS-staged x) ----------------
__global__ __launch_bounds__(256) void proj_mfma(const float* __restrict__ x,
                                                 const __bf16* __restrict__ wt,
                                                 __bf16* __restrict__ qb,
                                                 float* __restrict__ kout,
                                                 float* __restrict__ vout,
                                                 __bf16* __restrict__ kb,
                                                 __bf16* __restrict__ vtb) {
    __shared__ __bf16 xs[64][520];
    __shared__ __bf16 vls[4][64][24];
    const int tid = threadIdx.x;
    const int w = tid >> 6, lane = tid & 63;
    const int lo = lane & 15, hi = lane >> 4;
    const int r0 = (blockIdx.x * 4 + w) * 16;
    const int b = r0 >> 10;
    const int t0r = r0 & (TNEW - 1);

    {
        const float4* xg = (const float4*)(x + (size_t)blockIdx.x * 64 * EMB);
#pragma unroll
        for (int k = 0; k < 32; ++k) {
            const int f = tid + 256 * k;
            const int row = f >> 7, col4 = (f & 127) * 4;
            const float4 v = xg[f];
            bf16x4 t;
            t[0] = (__bf16)v.x; t[1] = (__bf16)v.y;
            t[2] = (__bf16)v.z; t[3] = (__bf16)v.w;
            *(bf16x4*)&xs[row][col4] = t;
        }
    }
    __syncthreads();

    for (int m = 0; m < 3; ++m) {
        const __bf16* wm = wt + (size_t)m * HD * EMB;
        f32x4 acc[4];
#pragma unroll
        for (int n = 0; n < 4; ++n) acc[n] = (f32x4){0.f, 0.f, 0.f, 0.f};
#pragma unroll
        for (int c = 0; c < 16; ++c) {
            const bf16x8 ax = *(const bf16x8*)&xs[w * 16 + lo][c * 32 + hi * 8];
#pragma unroll
            for (int n = 0; n < 4; ++n) {
                const bf16x8 bw = *(const bf16x8*)(wm + (size_t)(n * 16 + lo) * EMB + c * 32 + hi * 8);
                acc[n] = MFMA(ax, bw, acc[n]);
            }
        }
#pragma unroll
        for (int n = 0; n < 4; ++n) {
#pragma unroll
            for (int rr = 0; rr < 4; ++rr) {
                const int grow = r0 + hi * 4 + rr;
                const int t = grow & (TNEW - 1);
                const int d = n * 16 + lo;
                const float val = acc[n][rr];
                if (m == 0) {
                    qb[(size_t)grow * HD + d] = (__bf16)(val * QSCALE);
                } else if (m == 1) {
                    const size_t kv = ((size_t)b * TTOT + TCACHE + t) * HD + d;
                    kout[kv] = val;
                    kb[kv] = (__bf16)val;
                } else {
                    const size_t kv = ((size_t)b * TTOT + TCACHE + t) * HD + d;
                    vout[kv] = val;
                    vls[w][d][hi * 4 + rr] = (__bf16)val;
                }
            }
        }
    }
    __syncthreads();
    bf16x8 v0 = *(const bf16x8*)&vls[w][lane][0];
    bf16x8 v1 = *(const bf16x8*)&vls[w][lane][8];
    __bf16* vt = vtb + ((size_t)b * HD + lane) * TTOT + TCACHE + t0r;
    *(bf16x8*)vt = v0;
    *(bf16x8*)(vt + 8) = v1;
}

// ---------------- k3: flash attention, swapped-QK softmax, 4 waves x 32 rows ----------------
// grid 512 = 8 batches x 8 qblocks(128 rows) x 8 key-splits(512 keys); 2 blocks/CU
#define QB 128
#define NSPLIT 8
#define SKEYS 512
__global__ __launch_bounds__(256, 2) void attn_mfma(const __bf16* __restrict__ qb,
                                                    const __bf16* __restrict__ kb,
                                                    const __bf16* __restrict__ vtb,
                                                    __bf16* __restrict__ Opart,
                                                    float* __restrict__ mlpart) {
    __shared__ __align__(16) __bf16 Kt[2][64 * 64];      // 16 KB
    __shared__ __align__(16) __bf16 Vts[2][64 * 64];     // 16 KB
    __shared__ __align__(16) __bf16 P_lds[4][16][72];    // 9 KB

    const int tid = threadIdx.x;
    const int wv = tid >> 6, lane = tid & 63;
    const int lo = lane & 15, hi = lane >> 4;

    const int bid = blockIdx.x;
    const int b = bid & 7;                 // XCD-major
    const int idx = bid >> 3;              // 0..63
    const int split = idx & 7;
    const int qloc = idx >> 3;             // 0..7
    const int t0 = qloc * QB;
    const int row0 = b * TNEW + t0;

    const int s_begin = split * SKEYS;
    int count = ((TCACHE + t0 + QB - s_begin) + 63) >> 6;
    count = count < 0 ? 0 : (count > 8 ? 8 : count);

    const __bf16* Kb = kb + (size_t)b * TTOT * HD;
    const __bf16* Vb = vtb + (size_t)b * HD * TTOT;

    // staging: wave wv stages rows [wv*16, wv*16+16) of each 64-row tile (2 ops)
    const int r_sub = lane >> 3;                       // 0..7
    const int c_st = ((lane & 7) * 16) ^ (r_sub << 4); // pre-swizzled source byte col

    // Q fragments: wave owns 32 rows (2 groups of 16)
    const __bf16* Qw = qb + (size_t)(row0 + wv * 32) * HD;
    bf16x8 aq[2][2];
#pragma unroll
    for (int g = 0; g < 2; ++g) {
        aq[g][0] = *(const bf16x8*)(Qw + (size_t)(g * 16 + lo) * HD + hi * 8);
        aq[g][1] = *(const bf16x8*)(Qw + (size_t)(g * 16 + lo) * HD + 32 + hi * 8);
    }

    f32x4 o[2][4];
    float mg[2], lg[2];
#pragma unroll
    for (int g = 0; g < 2; ++g) {
#pragma unroll
        for (int n = 0; n < 4; ++n) o[g][n] = (f32x4){0.f, 0.f, 0.f, 0.f};
        mg[g] = -1e30f; lg[g] = 0.f;
    }

    if (count > 0) {
#pragma unroll
        for (int j = 0; j < 2; ++j) {
            const int row = wv * 16 + j * 8 + r_sub;
            const char* gk = (const char*)Kb + (size_t)(s_begin + row) * 128 + c_st;
            const char* gv = (const char*)Vb + ((size_t)row * TTOT + s_begin) * 2 + c_st;
            GLOAD_LDS16(gk, Kt[0] + (wv * 16 + j * 8) * 64);
            GLOAD_LDS16(gv, Vts[0] + (wv * 16 + j * 8) * 64);
        }
    }
    __syncthreads();

    const int sw = (lo & 7) << 3;   // element-level read swizzle

    for (int it = 0; it < count; ++it) {
        const int s0 = s_begin + it * 64;
        const int buf = it & 1;
        if (it + 1 < count) {
            const int sn = s0 + 64;
#pragma unroll
            for (int j = 0; j < 2; ++j) {
                const int row = wv * 16 + j * 8 + r_sub;
                const char* gk = (const char*)Kb + (size_t)(sn + row) * 128 + c_st;
                const char* gv = (const char*)Vb + ((size_t)row * TTOT + sn) * 2 + c_st;
                GLOAD_LDS16(gk, Kt[buf ^ 1] + (wv * 16 + j * 8) * 64);
                GLOAD_LDS16(gv, Vts[buf ^ 1] + (wv * 16 + j * 8) * 64);
            }
        }

        const __bf16* Kl = Kt[buf];
        const __bf16* Vl = Vts[buf];

        // K/V fragments (shared across both row-groups)
        bf16x8 bk[4][2], bv[4][2];
#pragma unroll
        for (int kg = 0; kg < 4; ++kg) {
            const int kr = (kg * 16 + lo) * 64;
            bk[kg][0] = *(const bf16x8*)(Kl + kr + ((hi * 8) ^ sw));
            bk[kg][1] = *(const bf16x8*)(Kl + kr + ((32 + hi * 8) ^ sw));
        }
#pragma unroll
        for (int n = 0; n < 4; ++n) {
            const int vr = (n * 16 + lo) * 64;
            bv[n][0] = *(const bf16x8*)(Vl + vr + ((hi * 8) ^ sw));
            bv[n][1] = *(const bf16x8*)(Vl + vr + ((32 + hi * 8) ^ sw));
        }

#pragma unroll
        for (int g = 0; g < 2; ++g) {
            const int tg = t0 + wv * 32 + g * 16;
            // ---- swapped QK^T: rows=keys, cols=q-rows; lane owns q-row `lo` ----
            const f32x4 z = (f32x4){0.f, 0.f, 0.f, 0.f};
            f32x4 sc[4];
#pragma unroll
            for (int kg = 0; kg < 4; ++kg) {
                sc[kg] = MFMA(bk[kg][0], aq[g][0], z);
                sc[kg] = MFMA(bk[kg][1], aq[g][1], sc[kg]);
            }

            if (s0 + 63 > TCACHE + tg) {
                const int lim = TCACHE + tg + lo;   // per-lane q-row limit
#pragma unroll
                for (int kg = 0; kg < 4; ++kg)
#pragma unroll
                    for (int rr = 0; rr < 4; ++rr)
                        if (s0 + kg * 16 + hi * 4 + rr > lim) sc[kg][rr] = -1e30f;
            }

            // ---- row max: 15 in-lane + 2 shuffles ----
            f32x4 mx = sc[0];
            mx = (f32x4){fmaxf(mx[0], sc[1][0]), fmaxf(mx[1], sc[1][1]),
                         fmaxf(mx[2], sc[1][2]), fmaxf(mx[3], sc[1][3])};
            mx = (f32x4){fmaxf(mx[0], sc[2][0]), fmaxf(mx[1], sc[2][1]),
                         fmaxf(mx[2], sc[2][2]), fmaxf(mx[3], sc[2][3])};
            mx = (f32x4){fmaxf(mx[0], sc[3][0]), fmaxf(mx[1], sc[3][1]),
                         fmaxf(mx[2], sc[3][2]), fmaxf(mx[3], sc[3][3])};
            float mt = fmaxf(fmaxf(mx[0], mx[1]), fmaxf(mx[2], mx[3]));
            mt = fmaxf(mt, __shfl_xor(mt, 16));
            mt = fmaxf(mt, __shfl_xor(mt, 32));

            if (__any(mt > mg[g] + 8.0f)) {          // defer-max rescale (rare)
                const float mn = fmaxf(mg[g], mt);
                const float corr = exp2f(mg[g] - mn);
                lg[g] *= corr;
                mg[g] = mn;
                float cb[4];
#pragma unroll
                for (int rr = 0; rr < 4; ++rr) cb[rr] = __shfl(corr, hi * 4 + rr);
#pragma unroll
                for (int n = 0; n < 4; ++n)
#pragma unroll
                    for (int rr = 0; rr < 4; ++rr) o[g][n][rr] *= cb[rr];
            }

            // ---- exp + sum + packed P write (4 x ds_write_b64) ----
            float ps = 0.f;
#pragma unroll
            for (int kg = 0; kg < 4; ++kg) {
                const float e0 = exp2f(sc[kg][0] - mg[g]);
                const float e1 = exp2f(sc[kg][1] - mg[g]);
                const float e2 = exp2f(sc[kg][2] - mg[g]);
                const float e3 = exp2f(sc[kg][3] - mg[g]);
                ps += (e0 + e1) + (e2 + e3);
                bf16x4 pk;
                pk[0] = (__bf16)e0; pk[1] = (__bf16)e1;
                pk[2] = (__bf16)e2; pk[3] = (__bf16)e3;
                *(bf16x4*)&P_lds[wv][lo][kg * 16 + hi * 4] = pk;
            }
            ps += __shfl_xor(ps, 16);
            ps += __shfl_xor(ps, 32);
            lg[g] += ps;
            asm volatile("" ::: "memory");

            // ---- PV: A = P[qrow][key] row-major, B = V frags ----
            const bf16x8 ap0 = *(const bf16x8*)&P_lds[wv][lo][hi * 8];
            const bf16x8 ap1 = *(const bf16x8*)&P_lds[wv][lo][32 + hi * 8];
#pragma unroll
            for (int n = 0; n < 4; ++n) o[g][n] = MFMA(ap0, bv[n][0], o[g][n]);
#pragma unroll
            for (int n = 0; n < 4; ++n) o[g][n] = MFMA(ap1, bv[n][1], o[g][n]);
            asm volatile("" ::: "memory");   // keep ap reads before next group's P writes
        }
        __syncthreads();
    }

    // ---- write partials ----
#pragma unroll
    for (int g = 0; g < 2; ++g) {
        __bf16* Ow = Opart + ((size_t)split * (NB * TNEW) + row0 + wv * 32 + g * 16) * HD;
#pragma unroll
        for (int n = 0; n < 4; ++n)
#pragma unroll
            for (int rr = 0; rr < 4; ++rr)
                Ow[(size_t)(hi * 4 + rr) * HD + n * 16 + lo] = (__bf16)o[g][n][rr];
        if (hi == 0) {
            float* mlw = mlpart + ((size_t)split * (NB * TNEW) + row0 + wv * 32 + g * 16) * 2;
            mlw[lo * 2]     = mg[g];
            mlw[lo * 2 + 1] = lg[g];
        }
    }
}

// ---------------- k4: combine key-split partials ----------------
__global__ __launch_bounds__(256) void combine(const __bf16* __restrict__ Opart,
                                               const float* __restrict__ mlpart,
                                               float* __restrict__ out) {
    const int e = blockIdx.x * 256 + threadIdx.x;
    const int row = e >> 6, d = e & 63;
    float mf = -1e30f;
#pragma unroll
    for (int s = 0; s < NSPLIT; ++s)
        mf = fmaxf(mf, mlpart[((size_t)s * (NB * TNEW) + row) * 2]);
    float lf = 0.f, acc = 0.f;
#pragma unroll
    for (int s = 0; s < NSPLIT; ++s) {
        const float ms = mlpart[((size_t)s * (NB * TNEW) + row) * 2];
        const float ls = mlpart[((size_t)s * (NB * TNEW) + row) * 2 + 1];
        const float f = exp2f(ms - mf);
        lf += ls * f;
        acc += (float)Opart[((size_t)s * (NB * TNEW) + row) * HD + d] * f;
    }
    out[e] = acc / lf;
}

extern "C" void kernel_launch(void* const* d_in, const int* in_sizes, int n_in,
                              void* d_out, int out_size, void* d_ws, size_t ws_size,
                              hipStream_t stream) {
    (void)in_sizes; (void)n_in; (void)out_size; (void)ws_size;
    const float* x  = (const float*)d_in[0];
    const float* ck = (const float*)d_in[2];
    const float* cv = (const float*)d_in[3];
    const float* Wq = (const float*)d_in[4];
    const float* Wk = (const float*)d_in[5];
    const float* Wv = (const float*)d_in[6];

    float* out  = (float*)d_out;
    float* kout = out + (size_t)NB * TNEW * HD;
    float* vout = kout + (size_t)NB * TTOT * HD;

    char* ws = (char*)d_ws;
    __bf16* wt  = (__bf16*)(ws + WS_WT);
    __bf16* kbf = (__bf16*)(ws + WS_KBF);
    __bf16* vtb = (__bf16*)(ws + WS_VTB);
    __bf16* Op  = (__bf16*)(ws + WS_OP);
    float*  ml  = (float*)(ws + WS_ML);
    __bf16* qb  = (__bf16*)d_out;

    prep<<<dim3(1176), dim3(256), 0, stream>>>(ck, cv, Wq, Wk, Wv, kout, vout, kbf, vtb, wt);
    proj_mfma<<<dim3(128), dim3(256), 0, stream>>>(x, wt, qb, kout, vout, kbf, vtb);
    attn_mfma<<<dim3(512), dim3(256), 0, stream>>>(qb, kbf, vtb, Op, ml);
    combine<<<dim3(2048), dim3(256), 0, stream>>>(Op, ml, out);
}

// Round 7
// 51.320 us; speedup vs baseline: 10.2474x; 1.2678x over previous
//
#include <hip/hip_runtime.h>

#define NB     8
#define TNEW   1024
#define TCACHE 3072
#define TTOT   4096
#define EMB    512
#define HD     64

typedef __bf16 bf16x8 __attribute__((ext_vector_type(8)));
typedef __bf16 bf16x4 __attribute__((ext_vector_type(4)));
typedef float  f32x4  __attribute__((ext_vector_type(4)));

#define MFMA(a,b,c) __builtin_amdgcn_mfma_f32_16x16x32_bf16((a),(b),(c),0,0,0)

#define GLOAD_LDS16(g, l) \
    __builtin_amdgcn_global_load_lds((const __attribute__((address_space(1))) void*)(g), \
                                     (__attribute__((address_space(3))) void*)(l), 16, 0, 0)

// log2-domain scale: 1/sqrt(64) * 1/ln(2)
#define QSCALE 0.180336880f

// ---------- ws layout (bytes) ----------
#define WS_WT   0          // 3*64*512*2 = 196608   WT[m][d][c] bf16
#define WS_KBF  196608     // 8*4096*64*2 = 4194304
#define WS_VTB  4390912    // 8*64*4096*2 = 4194304 (per batch: Vt[d][s])
#define WS_OP   8585216    // 8*8192*64*2 = 8388608 (bf16 [split][row][d])
#define WS_ML   16973824   // 8*8192*2*4  = 524288  (f32 [split][row][{m,l}], log2 domain)

// qb (bf16 q*QSCALE, [8192][64]) aliases d_out's out section (written last by combine).

// ---------------- k1: fused prep ----------------
__global__ __launch_bounds__(256) void prep(const float* __restrict__ ck,
                                            const float* __restrict__ cv,
                                            const float* __restrict__ Wq,
                                            const float* __restrict__ Wk,
                                            const float* __restrict__ Wv,
                                            float* __restrict__ kout,
                                            float* __restrict__ vout,
                                            __bf16* __restrict__ kb,
                                            __bf16* __restrict__ vtb,
                                            __bf16* __restrict__ wt) {
    const int blk = blockIdx.x;
    const int tid = threadIdx.x;
    if (blk < 768) {
#pragma unroll
        for (int it = 0; it < 2; ++it) {
            const int i = blk * 256 + tid + it * 196608;
            const int b = i / 49152;
            const int f = i - b * 49152;
            const int s = f >> 4, d = (f & 15) * 4;
            const float4 kd = ((const float4*)ck)[i];
            ((float4*)(kout + (size_t)b * TTOT * HD))[f] = kd;
            bf16x4 k4;
            k4[0] = (__bf16)kd.x; k4[1] = (__bf16)kd.y;
            k4[2] = (__bf16)kd.z; k4[3] = (__bf16)kd.w;
            *(bf16x4*)(kb + (size_t)b * TTOT * HD + s * HD + d) = k4;
        }
    } else if (blk < 1152) {
        __shared__ __bf16 vl[64][72];
        const int tb = blk - 768;
        const int b = tb / 48, si = tb - (tb / 48) * 48;
        const int sbase = si * 64;
        const float4* src = (const float4*)(cv + ((size_t)b * TCACHE + sbase) * HD);
        float4* dstf = (float4*)(vout + ((size_t)b * TTOT + sbase) * HD);
#pragma unroll
        for (int k = 0; k < 4; ++k) {
            const int f = tid + 256 * k;
            const int s = f >> 4, d4 = (f & 15) * 4;
            const float4 v = src[f];
            dstf[f] = v;
            bf16x4 t;
            t[0] = (__bf16)v.x; t[1] = (__bf16)v.y;
            t[2] = (__bf16)v.z; t[3] = (__bf16)v.w;
            *(bf16x4*)&vl[s][d4] = t;
        }
        __syncthreads();
        const int d = tid >> 2, sc = tid & 3;
        bf16x8 o0, o1;
#pragma unroll
        for (int i = 0; i < 8; ++i) {
            o0[i] = vl[sc * 16 + i][d];
            o1[i] = vl[sc * 16 + 8 + i][d];
        }
        __bf16* vt = vtb + ((size_t)b * HD + d) * TTOT + sbase + sc * 16;
        *(bf16x8*)vt = o0;
        *(bf16x8*)(vt + 8) = o1;
    } else {
        __shared__ __bf16 vl[64][72];
        const int tb = blk - 1152;                 // 0..23
        const int m = tb >> 3;
        const int ct = (tb & 7) * 64;
        const float* W = (m == 0) ? Wq : (m == 1) ? Wk : Wv;
        const float4* src = (const float4*)(W + (size_t)ct * HD);
#pragma unroll
        for (int k = 0; k < 4; ++k) {
            const int f = tid + 256 * k;
            const int c = f >> 4, d4 = (f & 15) * 4;
            const float4 v = src[f];
            bf16x4 t;
            t[0] = (__bf16)v.x; t[1] = (__bf16)v.y;
            t[2] = (__bf16)v.z; t[3] = (__bf16)v.w;
            *(bf16x4*)&vl[c][d4] = t;
        }
        __syncthreads();
        const int d = tid >> 2, sc = tid & 3;
        bf16x8 o0, o1;
#pragma unroll
        for (int i = 0; i < 8; ++i) {
            o0[i] = vl[sc * 16 + i][d];
            o1[i] = vl[sc * 16 + 8 + i][d];
        }
        __bf16* wr = wt + (size_t)m * HD * EMB + (size_t)d * EMB + ct + sc * 16;
        *(bf16x8*)wr = o0;
        *(bf16x8*)(wr + 8) = o1;
    }
}

// ---------------- k2: MFMA projections (2 waves/block, 32 rows, grid 256) ----------------
__global__ __launch_bounds__(128) void proj_mfma(const float* __restrict__ x,
                                                 const __bf16* __restrict__ wt,
                                                 __bf16* __restrict__ qb,
                                                 float* __restrict__ kout,
                                                 float* __restrict__ vout,
                                                 __bf16* __restrict__ kb,
                                                 __bf16* __restrict__ vtb) {
    __shared__ __bf16 xs[32][520];                 // 33 KB
    __shared__ __bf16 vls[2][64][24];              // 6 KB
    const int tid = threadIdx.x;
    const int w = tid >> 6, lane = tid & 63;
    const int lo = lane & 15, hi = lane >> 4;
    const int r0 = blockIdx.x * 32 + w * 16;
    const int b = r0 >> 10;
    const int t0r = r0 & (TNEW - 1);

    {   // stage 32x512 f32 -> bf16 LDS (coalesced)
        const float4* xg = (const float4*)(x + (size_t)blockIdx.x * 32 * EMB);
#pragma unroll
        for (int k = 0; k < 32; ++k) {
            const int f = tid + 128 * k;           // 0..4095
            const int row = f >> 7, col4 = (f & 127) * 4;
            const float4 v = xg[f];
            bf16x4 t;
            t[0] = (__bf16)v.x; t[1] = (__bf16)v.y;
            t[2] = (__bf16)v.z; t[3] = (__bf16)v.w;
            *(bf16x4*)&xs[row][col4] = t;
        }
    }
    __syncthreads();

    for (int m = 0; m < 3; ++m) {
        const __bf16* wm = wt + (size_t)m * HD * EMB;
        f32x4 acc[4];
#pragma unroll
        for (int n = 0; n < 4; ++n) acc[n] = (f32x4){0.f, 0.f, 0.f, 0.f};
#pragma unroll
        for (int c = 0; c < 16; ++c) {
            const bf16x8 ax = *(const bf16x8*)&xs[w * 16 + lo][c * 32 + hi * 8];
#pragma unroll
            for (int n = 0; n < 4; ++n) {
                const bf16x8 bw = *(const bf16x8*)(wm + (size_t)(n * 16 + lo) * EMB + c * 32 + hi * 8);
                acc[n] = MFMA(ax, bw, acc[n]);
            }
        }
#pragma unroll
        for (int n = 0; n < 4; ++n) {
#pragma unroll
            for (int rr = 0; rr < 4; ++rr) {
                const int grow = r0 + hi * 4 + rr;
                const int t = grow & (TNEW - 1);
                const int d = n * 16 + lo;
                const float val = acc[n][rr];
                if (m == 0) {
                    qb[(size_t)grow * HD + d] = (__bf16)(val * QSCALE);
                } else if (m == 1) {
                    const size_t kv = ((size_t)b * TTOT + TCACHE + t) * HD + d;
                    kout[kv] = val;
                    kb[kv] = (__bf16)val;
                } else {
                    const size_t kv = ((size_t)b * TTOT + TCACHE + t) * HD + d;
                    vout[kv] = val;
                    vls[w][d][hi * 4 + rr] = (__bf16)val;
                }
            }
        }
    }
    __syncthreads();
    bf16x8 v0 = *(const bf16x8*)&vls[w][lane][0];
    bf16x8 v1 = *(const bf16x8*)&vls[w][lane][8];
    __bf16* vt = vtb + ((size_t)b * HD + lane) * TTOT + TCACHE + t0r;
    *(bf16x8*)vt = v0;
    *(bf16x8*)(vt + 8) = v1;
}

// ---------------- k3: flash attention, swapped-QK, 8 waves x 16 rows ----------------
// grid 512 = 8 batches x 8 qblocks(128 rows) x 8 key-splits(512 keys)
// 512 thr = 8 waves -> 4096 waves total = 4 waves/SIMD
#define QB 128
#define NSPLIT 8
#define SKEYS 512
__global__ __launch_bounds__(512, 4) void attn_mfma(const __bf16* __restrict__ qb,
                                                    const __bf16* __restrict__ kb,
                                                    const __bf16* __restrict__ vtb,
                                                    __bf16* __restrict__ Opart,
                                                    float* __restrict__ mlpart) {
    __shared__ __align__(16) __bf16 Kt[2][64 * 64];      // 16 KB
    __shared__ __align__(16) __bf16 Vts[2][64 * 64];     // 16 KB
    __shared__ __align__(16) __bf16 P_lds[8][16][72];    // 18 KB

    const int tid = threadIdx.x;
    const int wv = tid >> 6, lane = tid & 63;
    const int lo = lane & 15, hi = lane >> 4;

    const int bid = blockIdx.x;
    const int b = bid & 7;                 // XCD-major
    const int idx = bid >> 3;              // 0..63
    const int split = idx & 7;
    const int qloc = idx >> 3;             // 0..7
    const int t0 = qloc * QB;
    const int row0 = b * TNEW + t0;

    const int s_begin = split * SKEYS;
    int count = ((TCACHE + t0 + QB - s_begin) + 63) >> 6;
    count = count < 0 ? 0 : (count > 8 ? 8 : count);

    const __bf16* Kb = kb + (size_t)b * TTOT * HD;
    const __bf16* Vb = vtb + (size_t)b * HD * TTOT;

    // staging: wave wv stages rows [wv*8, wv*8+8) of each 64-row tile (1 gload K + 1 V)
    const int r_sub = lane >> 3;                       // 0..7
    const int row_st = wv * 8 + r_sub;
    const int c_st = ((lane & 7) * 16) ^ (r_sub << 4); // pre-swizzled source byte col

    // Q: wave owns 16 rows
    const int t0w = t0 + wv * 16;
    const __bf16* Qw = qb + (size_t)(row0 + wv * 16) * HD;
    const bf16x8 aq0 = *(const bf16x8*)(Qw + (size_t)lo * HD + hi * 8);
    const bf16x8 aq1 = *(const bf16x8*)(Qw + (size_t)lo * HD + 32 + hi * 8);

    f32x4 o[4];
    float mg = -1e30f, lg = 0.f;
#pragma unroll
    for (int n = 0; n < 4; ++n) o[n] = (f32x4){0.f, 0.f, 0.f, 0.f};

    if (count > 0) {
        const char* gk = (const char*)Kb + (size_t)(s_begin + row_st) * 128 + c_st;
        const char* gv = (const char*)Vb + ((size_t)row_st * TTOT + s_begin) * 2 + c_st;
        GLOAD_LDS16(gk, Kt[0] + row_st * 64 - r_sub * 64 + r_sub * 64); // = Kt[0] + row_st*64
        GLOAD_LDS16(gv, Vts[0] + row_st * 64);
    }
    __syncthreads();

    const int sw = (lo & 7) << 3;   // element-level read swizzle

    for (int it = 0; it < count; ++it) {
        const int s0 = s_begin + it * 64;
        const int buf = it & 1;
        if (it + 1 < count) {
            const int sn = s0 + 64;
            const char* gk = (const char*)Kb + (size_t)(sn + row_st) * 128 + c_st;
            const char* gv = (const char*)Vb + ((size_t)row_st * TTOT + sn) * 2 + c_st;
            GLOAD_LDS16(gk, Kt[buf ^ 1] + row_st * 64);
            GLOAD_LDS16(gv, Vts[buf ^ 1] + row_st * 64);
        }

        const __bf16* Kl = Kt[buf];
        const __bf16* Vl = Vts[buf];

        bf16x8 bk[4][2], bv[4][2];
#pragma unroll
        for (int kg = 0; kg < 4; ++kg) {
            const int kr = (kg * 16 + lo) * 64;
            bk[kg][0] = *(const bf16x8*)(Kl + kr + ((hi * 8) ^ sw));
            bk[kg][1] = *(const bf16x8*)(Kl + kr + ((32 + hi * 8) ^ sw));
        }
#pragma unroll
        for (int n = 0; n < 4; ++n) {
            const int vr = (n * 16 + lo) * 64;
            bv[n][0] = *(const bf16x8*)(Vl + vr + ((hi * 8) ^ sw));
            bv[n][1] = *(const bf16x8*)(Vl + vr + ((32 + hi * 8) ^ sw));
        }

        // ---- swapped QK^T: rows=keys, cols=q-rows; lane owns q-row `lo` ----
        const f32x4 z = (f32x4){0.f, 0.f, 0.f, 0.f};
        f32x4 sc[4];
#pragma unroll
        for (int kg = 0; kg < 4; ++kg) {
            sc[kg] = MFMA(bk[kg][0], aq0, z);
            sc[kg] = MFMA(bk[kg][1], aq1, sc[kg]);
        }

        if (s0 + 63 > TCACHE + t0w) {
            const int lim = TCACHE + t0w + lo;   // per-lane q-row limit
#pragma unroll
            for (int kg = 0; kg < 4; ++kg)
#pragma unroll
                for (int rr = 0; rr < 4; ++rr)
                    if (s0 + kg * 16 + hi * 4 + rr > lim) sc[kg][rr] = -1e30f;
        }

        // ---- row max: 15 in-lane + 2 shuffles ----
        f32x4 mx = sc[0];
        mx = (f32x4){fmaxf(mx[0], sc[1][0]), fmaxf(mx[1], sc[1][1]),
                     fmaxf(mx[2], sc[1][2]), fmaxf(mx[3], sc[1][3])};
        mx = (f32x4){fmaxf(mx[0], sc[2][0]), fmaxf(mx[1], sc[2][1]),
                     fmaxf(mx[2], sc[2][2]), fmaxf(mx[3], sc[2][3])};
        mx = (f32x4){fmaxf(mx[0], sc[3][0]), fmaxf(mx[1], sc[3][1]),
                     fmaxf(mx[2], sc[3][2]), fmaxf(mx[3], sc[3][3])};
        float mt = fmaxf(fmaxf(mx[0], mx[1]), fmaxf(mx[2], mx[3]));
        mt = fmaxf(mt, __shfl_xor(mt, 16));
        mt = fmaxf(mt, __shfl_xor(mt, 32));

        if (__any(mt > mg + 8.0f)) {          // defer-max rescale (rare)
            const float mn = fmaxf(mg, mt);
            const float corr = exp2f(mg - mn);
            lg *= corr;
            mg = mn;
            float cb[4];
#pragma unroll
            for (int rr = 0; rr < 4; ++rr) cb[rr] = __shfl(corr, hi * 4 + rr);
#pragma unroll
            for (int n = 0; n < 4; ++n)
#pragma unroll
                for (int rr = 0; rr < 4; ++rr) o[n][rr] *= cb[rr];
        }

        // ---- exp + sum + packed P write (4 x ds_write_b64) ----
        float ps = 0.f;
#pragma unroll
        for (int kg = 0; kg < 4; ++kg) {
            const float e0 = exp2f(sc[kg][0] - mg);
            const float e1 = exp2f(sc[kg][1] - mg);
            const float e2 = exp2f(sc[kg][2] - mg);
            const float e3 = exp2f(sc[kg][3] - mg);
            ps += (e0 + e1) + (e2 + e3);
            bf16x4 pk;
            pk[0] = (__bf16)e0; pk[1] = (__bf16)e1;
            pk[2] = (__bf16)e2; pk[3] = (__bf16)e3;
            *(bf16x4*)&P_lds[wv][lo][kg * 16 + hi * 4] = pk;
        }
        ps += __shfl_xor(ps, 16);
        ps += __shfl_xor(ps, 32);
        lg += ps;
        asm volatile("" ::: "memory");

        // ---- PV: A = P[qrow][key] row-major, B = V frags ----
        const bf16x8 ap0 = *(const bf16x8*)&P_lds[wv][lo][hi * 8];
        const bf16x8 ap1 = *(const bf16x8*)&P_lds[wv][lo][32 + hi * 8];
#pragma unroll
        for (int n = 0; n < 4; ++n) o[n] = MFMA(ap0, bv[n][0], o[n]);
#pragma unroll
        for (int n = 0; n < 4; ++n) o[n] = MFMA(ap1, bv[n][1], o[n]);
        asm volatile("" ::: "memory");

        __syncthreads();
    }

    // ---- write partials ----
    __bf16* Ow = Opart + ((size_t)split * (NB * TNEW) + row0 + wv * 16) * HD;
#pragma unroll
    for (int n = 0; n < 4; ++n)
#pragma unroll
        for (int rr = 0; rr < 4; ++rr)
            Ow[(size_t)(hi * 4 + rr) * HD + n * 16 + lo] = (__bf16)o[n][rr];
    if (hi == 0) {
        float* mlw = mlpart + ((size_t)split * (NB * TNEW) + row0 + wv * 16) * 2;
        mlw[lo * 2]     = mg;
        mlw[lo * 2 + 1] = lg;
    }
}

// ---------------- k4: combine key-split partials ----------------
__global__ __launch_bounds__(256) void combine(const __bf16* __restrict__ Opart,
                                               const float* __restrict__ mlpart,
                                               float* __restrict__ out) {
    const int e = blockIdx.x * 256 + threadIdx.x;
    const int lane = threadIdx.x & 63;
    const int row = e >> 6, d = e & 63;
    // all 64 lanes of a wave share `row`; lane s<8 pattern: each lane loads split (lane&7)
    const float2 ml2 = *(const float2*)&mlpart[(((size_t)(lane & 7)) * (NB * TNEW) + row) * 2];
    float mf = -1e30f;
#pragma unroll
    for (int s = 0; s < NSPLIT; ++s) mf = fmaxf(mf, __shfl(ml2.x, s));
    float lf = 0.f, acc = 0.f;
#pragma unroll
    for (int s = 0; s < NSPLIT; ++s) {
        const float ms = __shfl(ml2.x, s);
        const float ls = __shfl(ml2.y, s);
        const float f = exp2f(ms - mf);
        lf += ls * f;
        acc += (float)Opart[((size_t)s * (NB * TNEW) + row) * HD + d] * f;
    }
    out[e] = acc / lf;
    (void)d;
}

extern "C" void kernel_launch(void* const* d_in, const int* in_sizes, int n_in,
                              void* d_out, int out_size, void* d_ws, size_t ws_size,
                              hipStream_t stream) {
    (void)in_sizes; (void)n_in; (void)out_size; (void)ws_size;
    const float* x  = (const float*)d_in[0];
    const float* ck = (const float*)d_in[2];
    const float* cv = (const float*)d_in[3];
    const float* Wq = (const float*)d_in[4];
    const float* Wk = (const float*)d_in[5];
    const float* Wv = (const float*)d_in[6];

    float* out  = (float*)d_out;
    float* kout = out + (size_t)NB * TNEW * HD;
    float* vout = kout + (size_t)NB * TTOT * HD;

    char* ws = (char*)d_ws;
    __bf16* wt  = (__bf16*)(ws + WS_WT);
    __bf16* kbf = (__bf16*)(ws + WS_KBF);
    __bf16* vtb = (__bf16*)(ws + WS_VTB);
    __bf16* Op  = (__bf16*)(ws + WS_OP);
    float*  ml  = (float*)(ws + WS_ML);
    __bf16* qb  = (__bf16*)d_out;

    prep<<<dim3(1176), dim3(256), 0, stream>>>(ck, cv, Wq, Wk, Wv, kout, vout, kbf, vtb, wt);
    proj_mfma<<<dim3(256), dim3(128), 0, stream>>>(x, wt, qb, kout, vout, kbf, vtb);
    attn_mfma<<<dim3(512), dim3(512), 0, stream>>>(qb, kbf, vtb, Op, ml);
    combine<<<dim3(2048), dim3(256), 0, stream>>>(Op, ml, out);
}